// Round 5
// baseline (452.082 us; speedup 1.0000x reference)
//
#include <hip/hip_runtime.h>
#include <math.h>

#define SEQ 4096
#define CH  256
#define NHT 8      // N * HEADS
#define DHD 64

using bf16x8 = __attribute__((ext_vector_type(8))) short;
using f32x4  = __attribute__((ext_vector_type(4))) float;
typedef unsigned short u16;
typedef unsigned int   u32;

__device__ __forceinline__ u16 f2bf(float f) {
    u32 u = __float_as_uint(f);
    u = (u + 0x7fffu + ((u >> 16) & 1u)) >> 16;
    return (u16)u;
}
__device__ __forceinline__ float bf2f(u16 h) {
    return __uint_as_float(((u32)h) << 16);
}

// ---------------------------------------------------------------------------
// Weight pack (transposed for NT GEMM).
// ---------------------------------------------------------------------------
__global__ __launch_bounds__(256) void k_pack(const float* __restrict__ WQ,
                                              const float* __restrict__ WK,
                                              const float* __restrict__ WV,
                                              const float* __restrict__ W1,
                                              const float* __restrict__ W2,
                                              u16* __restrict__ BtQKV,
                                              u16* __restrict__ W1t,
                                              u16* __restrict__ W2t)
{
    int id = blockIdx.x * 256 + threadIdx.x;
    if (id < 768 * 256) {
        int j = id >> 8, c = id & 255;
        int which = j >> 8, h = (j >> 6) & 3, d = j & 63;
        const float* W = (which == 0) ? WQ : (which == 1) ? WK : WV;
        BtQKV[id] = f2bf(W[(h * 256 + c) * 64 + d]);
    } else if (id < 768 * 256 + 65536) {
        int jj = id - 768 * 256;
        int j = jj >> 8, c = jj & 255;
        W1t[jj] = f2bf(W1[c * 256 + j]);
    } else if (id < 768 * 256 + 2 * 65536) {
        int jj = id - 768 * 256 - 65536;
        int j = jj >> 8, c = jj & 255;
        W2t[jj] = f2bf(W2[c * 256 + j]);
    }
}

// ---------------------------------------------------------------------------
// LN1 (R2-proven): x [N][C][S] -> norm bf16 [N][S][C]. 32 s-rows per block.
// ---------------------------------------------------------------------------
__global__ __launch_bounds__(256) void k_ln1(const float* __restrict__ x,
                                             const float* __restrict__ w,
                                             const float* __restrict__ b,
                                             u16* __restrict__ norm)
{
    __shared__ float tile[32][257];
    __shared__ float mu[32], rs[32];
    int n = blockIdx.y, s0 = blockIdx.x * 32;
    int t = threadIdx.x;
    int sl = t & 31, cg = t >> 5;
    for (int cc = 0; cc < 256; cc += 8) {
        int c = cc + cg;
        tile[sl][c] = x[(n * 256 + c) * SEQ + s0 + sl];
    }
    __syncthreads();
    int wv = t >> 6, l = t & 63;
    for (int rr = 0; rr < 8; rr++) {
        int s = wv * 8 + rr;
        float a0 = tile[s][l], a1 = tile[s][l + 64], a2 = tile[s][l + 128], a3 = tile[s][l + 192];
        float sm = a0 + a1 + a2 + a3;
        float sq = a0 * a0 + a1 * a1 + a2 * a2 + a3 * a3;
        for (int off = 32; off; off >>= 1) { sm += __shfl_xor(sm, off); sq += __shfl_xor(sq, off); }
        if (l == 0) {
            float m = sm * (1.f / 256.f);
            mu[s] = m;
            rs[s] = rsqrtf(sq * (1.f / 256.f) - m * m + 1e-5f);
        }
    }
    __syncthreads();
    float ww = w[t & 255], bb = b[t & 255];
    for (int s = 0; s < 32; s++) {
        float v = (tile[s][t] - mu[s]) * rs[s] * ww + bb;
        norm[(n * SEQ + s0 + s) * 256 + t] = f2bf(v);
    }
}

// ---------------------------------------------------------------------------
// QKV projection, barrier-free (R4-proven).
// ---------------------------------------------------------------------------
__global__ __launch_bounds__(256) void k_qkv(const u16* __restrict__ norm,
                                             const u16* __restrict__ Bt,
                                             u16* __restrict__ Qo,
                                             u16* __restrict__ Ko,
                                             u16* __restrict__ Vo)
{
    int m0 = blockIdx.x * 64, j0 = blockIdx.y * 128;
    int t = threadIdx.x, w = t >> 6, lane = t & 63, quad = lane >> 4, l16 = lane & 15;
    const u16* Ap = norm + (long)(m0 + w * 16 + l16) * 256;
    const u16* Bp = Bt + (long)j0 * 256;
    f32x4 z = {0.f, 0.f, 0.f, 0.f};
    f32x4 acc[8];
    #pragma unroll
    for (int j = 0; j < 8; j++) acc[j] = z;
    #pragma unroll
    for (int kc = 0; kc < 8; kc++) {
        bf16x8 a = *(const bf16x8*)&Ap[kc * 32 + quad * 8];
        #pragma unroll
        for (int j = 0; j < 8; j++) {
            bf16x8 b = *(const bf16x8*)&Bp[(long)(j * 16 + l16) * 256 + kc * 32 + quad * 8];
            acc[j] = __builtin_amdgcn_mfma_f32_16x16x32_bf16(a, b, acc[j], 0, 0, 0);
        }
    }
    #pragma unroll
    for (int j = 0; j < 8; j++) {
        int col = j0 + j * 16 + l16;
        int which = col >> 8, h = (col >> 6) & 3, d = col & 63;
        u16* dst = (which == 0) ? Qo : (which == 1) ? Ko : Vo;
        #pragma unroll
        for (int r = 0; r < 4; r++) {
            int m = m0 + w * 16 + quad * 4 + r;
            int n = m >> 12, s = m & 4095;
            dst[((n * 4 + h) * SEQ + s) * 64 + d] = f2bf(acc[j][r]);
        }
    }
}

// ---------------------------------------------------------------------------
// Pass 1 (R2-proven): partial column sums D4[qc][nh][k] = sum_q exp(QK^T/64).
// ---------------------------------------------------------------------------
__global__ __launch_bounds__(256) void k_pass1(const u16* __restrict__ Q,
                                               const u16* __restrict__ Km,
                                               float* __restrict__ D4)
{
    __shared__ __align__(16) u16 lQ[128][72];
    int nh = blockIdx.y, k0 = blockIdx.x * 128, qc = blockIdx.z;
    const u16* Qh = Q + (long)nh * SEQ * 64;
    const u16* Kh = Km + (long)nh * SEQ * 64;
    int t = threadIdx.x, w = t >> 6, lane = t & 63, quad = lane >> 4, l16 = lane & 15;
    bf16x8 Kf[2][2];
    #pragma unroll
    for (int i = 0; i < 2; i++)
        #pragma unroll
        for (int ch = 0; ch < 2; ch++)
            Kf[i][ch] = *(const bf16x8*)&Kh[(k0 + w * 32 + i * 16 + l16) * 64 + ch * 32 + quad * 8];
    f32x4 z = {0.f, 0.f, 0.f, 0.f};
    float Dacc[2][4] = {{0.f, 0.f, 0.f, 0.f}, {0.f, 0.f, 0.f, 0.f}};
    const float C = 0.015625f * 1.44269504088896f;   // log2(e)/64
    for (int q0 = qc * 1024; q0 < qc * 1024 + 1024; q0 += 128) {
        #pragma unroll
        for (int p = 0; p < 4; p++) {
            int idx = t + p * 256;
            int row = idx >> 3, cc = (idx & 7) * 8;
            *(uint4*)&lQ[row][cc] = *(const uint4*)&Qh[(q0 + row) * 64 + cc];
        }
        __syncthreads();
        #pragma unroll
        for (int j = 0; j < 8; j++) {
            bf16x8 b0 = *(const bf16x8*)&lQ[j * 16 + l16][quad * 8];
            bf16x8 b1 = *(const bf16x8*)&lQ[j * 16 + l16][32 + quad * 8];
            #pragma unroll
            for (int i = 0; i < 2; i++) {
                f32x4 acc = z;
                acc = __builtin_amdgcn_mfma_f32_16x16x32_bf16(Kf[i][0], b0, acc, 0, 0, 0);
                acc = __builtin_amdgcn_mfma_f32_16x16x32_bf16(Kf[i][1], b1, acc, 0, 0, 0);
                #pragma unroll
                for (int r = 0; r < 4; r++) Dacc[i][r] += exp2f(acc[r] * C);
            }
        }
        __syncthreads();
    }
    #pragma unroll
    for (int i = 0; i < 2; i++)
        #pragma unroll
        for (int r = 0; r < 4; r++) {
            float v = Dacc[i][r];
            v += __shfl_xor(v, 1); v += __shfl_xor(v, 2);
            v += __shfl_xor(v, 4); v += __shfl_xor(v, 8);
            if (l16 == 0)
                D4[((long)(qc * NHT + nh)) * SEQ + k0 + w * 32 + i * 16 + quad * 4 + r] = v;
        }
}

// ---------------------------------------------------------------------------
// Scale+transpose V (R2-proven): Vt[nh][d][k] = V[nh][k][d] / D[nh][k].
// ---------------------------------------------------------------------------
__global__ __launch_bounds__(256) void k_scaleV(const u16* __restrict__ V,
                                                const float* __restrict__ D4,
                                                u16* __restrict__ Vt)
{
    __shared__ float tile[64][65];
    int nh = blockIdx.y, k0 = blockIdx.x * 64;
    int t = threadIdx.x;
    int d = t & 63, kk = t >> 6;
    const u16* Vh = V + (long)nh * SEQ * 64;
    for (int p = 0; p < 16; p++) {
        int k = p * 4 + kk;
        float Dv = D4[((long)(0 * NHT + nh)) * SEQ + k0 + k]
                 + D4[((long)(1 * NHT + nh)) * SEQ + k0 + k]
                 + D4[((long)(2 * NHT + nh)) * SEQ + k0 + k]
                 + D4[((long)(3 * NHT + nh)) * SEQ + k0 + k];
        tile[k][d] = bf2f(Vh[(k0 + k) * 64 + d]) * (1.f / Dv);
    }
    __syncthreads();
    int k2 = t & 63, d4 = t >> 6;
    u16* Vth = Vt + (long)nh * 64 * SEQ;
    for (int p = 0; p < 16; p++) {
        int dd = p * 4 + d4;
        Vth[dd * SEQ + k0 + k2] = f2bf(tile[k2][dd]);
    }
}

// ---------------------------------------------------------------------------
// Pass 2, WAVE-INDEPENDENT (zero barriers). Each wave owns 16 q-rows:
//   ST: for each of 8 k-subtiles (16 k each), A = K frags from global (L1-
//       resident, shared across waves), B = this wave's Q frags (registers).
//       C-layout gives each lane 4 consecutive k for one q -> one packed
//       uint2 store into the wave's PRIVATE lP strip. No cross-wave data.
//   PV: read own lP as b128 A-frags, Vt frags from global, accumulate.
// Within-wave LDS ordering is lgkmcnt (compiler-inserted) — no __syncthreads.
// Grid (64 q-tiles, 8 nh, 4 k-chunks); partials to acat4.
// ---------------------------------------------------------------------------
__global__ __launch_bounds__(256) void k_pass2(const u16* __restrict__ Q,
                                               const u16* __restrict__ Km,
                                               const u16* __restrict__ Vt,
                                               float* __restrict__ acat4)
{
    __shared__ __align__(16) u16 lP[4][16][140];
    int nh = blockIdx.y, q0 = blockIdx.x * 64, kcid = blockIdx.z;
    int kbase = kcid * 1024;
    int n = nh >> 2, h = nh & 3;
    const u16* Qh = Q + (long)nh * SEQ * 64;
    const u16* Kh = Km + (long)nh * SEQ * 64;
    const u16* Vh = Vt + (long)nh * 64 * SEQ;
    int t = threadIdx.x, w = t >> 6, lane = t & 63, quad = lane >> 4, l16 = lane & 15;
    // This wave's Q fragments: q rows [q0 + w*16, +16)
    bf16x8 Qf0 = *(const bf16x8*)&Qh[(q0 + w * 16 + l16) * 64 + quad * 8];
    bf16x8 Qf1 = *(const bf16x8*)&Qh[(q0 + w * 16 + l16) * 64 + 32 + quad * 8];
    f32x4 z = {0.f, 0.f, 0.f, 0.f};
    f32x4 accO[4];
    #pragma unroll
    for (int jd = 0; jd < 4; jd++) accO[jd] = z;
    const float C = 0.015625f * 1.44269504088896f;   // log2(e)/64

    for (int k0 = kbase; k0 < kbase + 1024; k0 += 128) {
        // ST: 8 k-subtiles x 16 q (this wave)
        #pragma unroll
        for (int i = 0; i < 8; i++) {
            bf16x8 a0 = *(const bf16x8*)&Kh[(k0 + i * 16 + l16) * 64 + quad * 8];
            bf16x8 a1 = *(const bf16x8*)&Kh[(k0 + i * 16 + l16) * 64 + 32 + quad * 8];
            f32x4 acc = z;
            acc = __builtin_amdgcn_mfma_f32_16x16x32_bf16(a0, Qf0, acc, 0, 0, 0);
            acc = __builtin_amdgcn_mfma_f32_16x16x32_bf16(a1, Qf1, acc, 0, 0, 0);
            // rows (k) = i*16 + quad*4 + r, col (q) = l16: pack 4 k into uint2
            u32 e0 = __float_as_uint(exp2f(acc[0] * C));
            u32 e1 = __float_as_uint(exp2f(acc[1] * C));
            u32 e2 = __float_as_uint(exp2f(acc[2] * C));
            u32 e3 = __float_as_uint(exp2f(acc[3] * C));
            uint2 pk;
            pk.x = ((e0 + 0x8000u) >> 16) | ((e1 + 0x8000u) & 0xffff0000u);
            pk.y = ((e2 + 0x8000u) >> 16) | ((e3 + 0x8000u) & 0xffff0000u);
            *(uint2*)&lP[w][l16][i * 16 + quad * 4] = pk;
        }
        // PV: read own strip (lgkmcnt ordering, no barrier)
        #pragma unroll
        for (int kc = 0; kc < 4; kc++) {
            bf16x8 pa = *(const bf16x8*)&lP[w][l16][kc * 32 + quad * 8];
            #pragma unroll
            for (int jd = 0; jd < 4; jd++) {
                bf16x8 vb = *(const bf16x8*)&Vh[(jd * 16 + l16) * SEQ + k0 + kc * 32 + quad * 8];
                accO[jd] = __builtin_amdgcn_mfma_f32_16x16x32_bf16(pa, vb, accO[jd], 0, 0, 0);
            }
        }
    }
    float* dst = acat4 + (long)kcid * 8192 * 256;
    #pragma unroll
    for (int jd = 0; jd < 4; jd++)
        #pragma unroll
        for (int r = 0; r < 4; r++) {
            int s = q0 + w * 16 + quad * 4 + r;
            int c = h * 64 + jd * 16 + l16;
            dst[((long)n * SEQ + s) * 256 + c] = accO[jd][r];
        }
}

// ---------------------------------------------------------------------------
// LN2 + partial-sum fold: reads 4 pass-2 partials, writes summed acat (for
// mlp2 residual) and h2 = LN(x^T + acat) bf16.
// ---------------------------------------------------------------------------
__global__ __launch_bounds__(256) void k_ln2(const float* __restrict__ x,
                                             const float* __restrict__ acat4,
                                             const float* __restrict__ w,
                                             const float* __restrict__ b,
                                             u16* __restrict__ h2,
                                             float* __restrict__ acat)
{
    __shared__ float tile[32][257];
    __shared__ float mu[32], rs[32];
    int n = blockIdx.y, s0 = blockIdx.x * 32;
    int t = threadIdx.x;
    int sl = t & 31, cg = t >> 5;
    for (int cc = 0; cc < 256; cc += 8) {
        int c = cc + cg;
        tile[sl][c] = x[(n * 256 + c) * SEQ + s0 + sl];
    }
    __syncthreads();
    const long STRIDE = (long)8192 * 256;
    for (int s = 0; s < 32; s++) {
        long idx = ((long)n * SEQ + s0 + s) * 256 + t;
        float a = acat4[idx] + acat4[idx + STRIDE] + acat4[idx + 2 * STRIDE] + acat4[idx + 3 * STRIDE];
        acat[idx] = a;
        tile[s][t] += a;
    }
    __syncthreads();
    int wv = t >> 6, l = t & 63;
    for (int rr = 0; rr < 8; rr++) {
        int s = wv * 8 + rr;
        float a0 = tile[s][l], a1 = tile[s][l + 64], a2 = tile[s][l + 128], a3 = tile[s][l + 192];
        float sm = a0 + a1 + a2 + a3;
        float sq = a0 * a0 + a1 * a1 + a2 * a2 + a3 * a3;
        for (int off = 32; off; off >>= 1) { sm += __shfl_xor(sm, off); sq += __shfl_xor(sq, off); }
        if (l == 0) {
            float m = sm * (1.f / 256.f);
            mu[s] = m;
            rs[s] = rsqrtf(sq * (1.f / 256.f) - m * m + 1e-5f);
        }
    }
    __syncthreads();
    float ww = w[t], bb = b[t];
    for (int s = 0; s < 32; s++) {
        float v = (tile[s][t] - mu[s]) * rs[s] * ww + bb;
        h2[((long)n * SEQ + s0 + s) * 256 + t] = f2bf(v);
    }
}

// ---------------------------------------------------------------------------
// MLP1, barrier-free (R4-proven).
// ---------------------------------------------------------------------------
__global__ __launch_bounds__(256) void k_mlp1(const u16* __restrict__ h2,
                                              const u16* __restrict__ W1t,
                                              const float* __restrict__ b1,
                                              u16* __restrict__ tbuf)
{
    int m0 = blockIdx.x * 64, j0 = blockIdx.y * 128;
    int t = threadIdx.x, w = t >> 6, lane = t & 63, quad = lane >> 4, l16 = lane & 15;
    const u16* Ap = h2 + (long)(m0 + w * 16 + l16) * 256;
    const u16* Bp = W1t + (long)j0 * 256;
    f32x4 z = {0.f, 0.f, 0.f, 0.f};
    f32x4 acc[8];
    #pragma unroll
    for (int j = 0; j < 8; j++) acc[j] = z;
    #pragma unroll
    for (int kc = 0; kc < 8; kc++) {
        bf16x8 a = *(const bf16x8*)&Ap[kc * 32 + quad * 8];
        #pragma unroll
        for (int j = 0; j < 8; j++) {
            bf16x8 b = *(const bf16x8*)&Bp[(long)(j * 16 + l16) * 256 + kc * 32 + quad * 8];
            acc[j] = __builtin_amdgcn_mfma_f32_16x16x32_bf16(a, b, acc[j], 0, 0, 0);
        }
    }
    #pragma unroll
    for (int j = 0; j < 8; j++) {
        int col = j0 + j * 16 + l16;
        float bj = b1[col];
        #pragma unroll
        for (int r = 0; r < 4; r++) {
            int m = m0 + w * 16 + quad * 4 + r;
            float v = acc[j][r] + bj;
            float g = 0.5f * v * (1.f + erff(v * 0.70710678118f));
            tbuf[(long)m * 256 + col] = f2bf(g);
        }
    }
}

// ---------------------------------------------------------------------------
// MLP2 + residual + fused output transpose (R4-proven).
// ---------------------------------------------------------------------------
__global__ __launch_bounds__(256) void k_mlp2(const u16* __restrict__ tbuf,
                                              const u16* __restrict__ W2t,
                                              const float* __restrict__ b2,
                                              const float* __restrict__ acat,
                                              float* __restrict__ out)
{
    __shared__ float LT[128][68];
    int m0 = blockIdx.x * 64, j0 = blockIdx.y * 128;
    int t = threadIdx.x, w = t >> 6, lane = t & 63, quad = lane >> 4, l16 = lane & 15;
    const u16* Ap = tbuf + (long)(m0 + w * 16 + l16) * 256;
    const u16* Bp = W2t + (long)j0 * 256;
    f32x4 z = {0.f, 0.f, 0.f, 0.f};
    f32x4 acc[8];
    #pragma unroll
    for (int j = 0; j < 8; j++) acc[j] = z;
    #pragma unroll
    for (int kc = 0; kc < 8; kc++) {
        bf16x8 a = *(const bf16x8*)&Ap[kc * 32 + quad * 8];
        #pragma unroll
        for (int j = 0; j < 8; j++) {
            bf16x8 b = *(const bf16x8*)&Bp[(long)(j * 16 + l16) * 256 + kc * 32 + quad * 8];
            acc[j] = __builtin_amdgcn_mfma_f32_16x16x32_bf16(a, b, acc[j], 0, 0, 0);
        }
    }
    #pragma unroll
    for (int j = 0; j < 8; j++) {
        int col = j0 + j * 16 + l16;
        float bj = b2[col];
        #pragma unroll
        for (int r = 0; r < 4; r++) {
            int m = m0 + w * 16 + quad * 4 + r;
            float v = acc[j][r] + bj + acat[(long)m * 256 + col];
            LT[j * 16 + l16][w * 16 + quad * 4 + r] = v;
        }
    }
    __syncthreads();
    int n = m0 >> 12, sbase = m0 & 4095;
    #pragma unroll
    for (int p = 0; p < 8; p++) {
        int row = p * 16 + (t >> 4);
        int ch = (t & 15) * 4;
        float4 v = *(float4*)&LT[row][ch];
        *(float4*)&out[((long)n * 256 + j0 + row) * SEQ + sbase + ch] = v;
    }
}

// ---------------------------------------------------------------------------
extern "C" void kernel_launch(void* const* d_in, const int* in_sizes, int n_in,
                              void* d_out, int out_size, void* d_ws, size_t ws_size,
                              hipStream_t stream) {
    const float* x    = (const float*)d_in[0];
    const float* ln1w = (const float*)d_in[1];
    const float* ln1b = (const float*)d_in[2];
    const float* WQ   = (const float*)d_in[3];
    const float* WK   = (const float*)d_in[4];
    const float* WV   = (const float*)d_in[5];
    const float* ln2w = (const float*)d_in[6];
    const float* ln2b = (const float*)d_in[7];
    const float* W1   = (const float*)d_in[8];
    const float* b1   = (const float*)d_in[9];
    const float* W2   = (const float*)d_in[10];
    const float* b2   = (const float*)d_in[11];
    float* out = (float*)d_out;

    char* p = (char*)d_ws;
    u16* norm   = (u16*)p;   p += (size_t)8192 * 256 * 2;
    u16* BtQKV  = (u16*)p;   p += (size_t)768 * 256 * 2;
    u16* W1t    = (u16*)p;   p += (size_t)256 * 256 * 2;
    u16* W2t    = (u16*)p;   p += (size_t)256 * 256 * 2;
    u16* Qb     = (u16*)p;   p += (size_t)NHT * SEQ * 64 * 2;
    u16* Kb     = (u16*)p;   p += (size_t)NHT * SEQ * 64 * 2;
    u16* Vb     = (u16*)p;   p += (size_t)NHT * SEQ * 64 * 2;
    float* D4   = (float*)p; p += (size_t)4 * NHT * SEQ * 4;
    u16* Vt     = (u16*)p;   p += (size_t)NHT * SEQ * 64 * 2;
    float* acat4= (float*)p; p += (size_t)4 * 8192 * 256 * 4;
    float* acat = (float*)p; p += (size_t)8192 * 256 * 4;
    u16* h2     = (u16*)p;   p += (size_t)8192 * 256 * 2;
    u16* tbuf   = (u16*)p;   p += (size_t)8192 * 256 * 2;

    k_pack<<<1280, 256, 0, stream>>>(WQ, WK, WV, W1, W2, BtQKV, W1t, W2t);
    k_ln1<<<dim3(128, 2), 256, 0, stream>>>(x, ln1w, ln1b, norm);
    k_qkv<<<dim3(128, 6), 256, 0, stream>>>(norm, BtQKV, Qb, Kb, Vb);
    k_pass1<<<dim3(32, 8, 4), 256, 0, stream>>>(Qb, Kb, D4);
    k_scaleV<<<dim3(64, 8), 256, 0, stream>>>(Vb, D4, Vt);
    k_pass2<<<dim3(64, 8, 4), 256, 0, stream>>>(Qb, Kb, Vt, acat4);
    k_ln2<<<dim3(128, 2), 256, 0, stream>>>(x, acat4, ln2w, ln2b, h2, acat);
    k_mlp1<<<dim3(128, 2), 256, 0, stream>>>(h2, W1t, b1, tbuf);
    k_mlp2<<<dim3(128, 2), 256, 0, stream>>>(tbuf, W2t, b2, acat, out);
}

// Round 6
// 311.962 us; speedup vs baseline: 1.4492x; 1.4492x over previous
//
#include <hip/hip_runtime.h>
#include <math.h>

#define SEQ 4096
#define CH  256
#define NHT 8      // N * HEADS
#define DHD 64

using bf16x8 = __attribute__((ext_vector_type(8))) short;
using f32x4  = __attribute__((ext_vector_type(4))) float;
typedef unsigned short u16;
typedef unsigned int   u32;

__device__ __forceinline__ u16 f2bf(float f) {
    u32 u = __float_as_uint(f);
    u = (u + 0x7fffu + ((u >> 16) & 1u)) >> 16;
    return (u16)u;
}
__device__ __forceinline__ float bf2f(u16 h) {
    return __uint_as_float(((u32)h) << 16);
}

// ---------------------------------------------------------------------------
// Weight pack (transposed for NT GEMM).
// ---------------------------------------------------------------------------
__global__ __launch_bounds__(256) void k_pack(const float* __restrict__ WQ,
                                              const float* __restrict__ WK,
                                              const float* __restrict__ WV,
                                              const float* __restrict__ W1,
                                              const float* __restrict__ W2,
                                              u16* __restrict__ BtQKV,
                                              u16* __restrict__ W1t,
                                              u16* __restrict__ W2t)
{
    int id = blockIdx.x * 256 + threadIdx.x;
    if (id < 768 * 256) {
        int j = id >> 8, c = id & 255;
        int which = j >> 8, h = (j >> 6) & 3, d = j & 63;
        const float* W = (which == 0) ? WQ : (which == 1) ? WK : WV;
        BtQKV[id] = f2bf(W[(h * 256 + c) * 64 + d]);
    } else if (id < 768 * 256 + 65536) {
        int jj = id - 768 * 256;
        int j = jj >> 8, c = jj & 255;
        W1t[jj] = f2bf(W1[c * 256 + j]);
    } else if (id < 768 * 256 + 2 * 65536) {
        int jj = id - 768 * 256 - 65536;
        int j = jj >> 8, c = jj & 255;
        W2t[jj] = f2bf(W2[c * 256 + j]);
    }
}

// ---------------------------------------------------------------------------
// LN1 (R2-proven): x [N][C][S] -> norm bf16 [N][S][C]. 32 s-rows per block.
// ---------------------------------------------------------------------------
__global__ __launch_bounds__(256) void k_ln1(const float* __restrict__ x,
                                             const float* __restrict__ w,
                                             const float* __restrict__ b,
                                             u16* __restrict__ norm)
{
    __shared__ float tile[32][257];
    __shared__ float mu[32], rs[32];
    int n = blockIdx.y, s0 = blockIdx.x * 32;
    int t = threadIdx.x;
    int sl = t & 31, cg = t >> 5;
    for (int cc = 0; cc < 256; cc += 8) {
        int c = cc + cg;
        tile[sl][c] = x[(n * 256 + c) * SEQ + s0 + sl];
    }
    __syncthreads();
    int wv = t >> 6, l = t & 63;
    for (int rr = 0; rr < 8; rr++) {
        int s = wv * 8 + rr;
        float a0 = tile[s][l], a1 = tile[s][l + 64], a2 = tile[s][l + 128], a3 = tile[s][l + 192];
        float sm = a0 + a1 + a2 + a3;
        float sq = a0 * a0 + a1 * a1 + a2 * a2 + a3 * a3;
        for (int off = 32; off; off >>= 1) { sm += __shfl_xor(sm, off); sq += __shfl_xor(sq, off); }
        if (l == 0) {
            float m = sm * (1.f / 256.f);
            mu[s] = m;
            rs[s] = rsqrtf(sq * (1.f / 256.f) - m * m + 1e-5f);
        }
    }
    __syncthreads();
    float ww = w[t & 255], bb = b[t & 255];
    for (int s = 0; s < 32; s++) {
        float v = (tile[s][t] - mu[s]) * rs[s] * ww + bb;
        norm[(n * SEQ + s0 + s) * 256 + t] = f2bf(v);
    }
}

// ---------------------------------------------------------------------------
// QKV projection, barrier-free (R4-proven).
// ---------------------------------------------------------------------------
__global__ __launch_bounds__(256) void k_qkv(const u16* __restrict__ norm,
                                             const u16* __restrict__ Bt,
                                             u16* __restrict__ Qo,
                                             u16* __restrict__ Ko,
                                             u16* __restrict__ Vo)
{
    int m0 = blockIdx.x * 64, j0 = blockIdx.y * 128;
    int t = threadIdx.x, w = t >> 6, lane = t & 63, quad = lane >> 4, l16 = lane & 15;
    const u16* Ap = norm + (long)(m0 + w * 16 + l16) * 256;
    const u16* Bp = Bt + (long)j0 * 256;
    f32x4 z = {0.f, 0.f, 0.f, 0.f};
    f32x4 acc[8];
    #pragma unroll
    for (int j = 0; j < 8; j++) acc[j] = z;
    #pragma unroll
    for (int kc = 0; kc < 8; kc++) {
        bf16x8 a = *(const bf16x8*)&Ap[kc * 32 + quad * 8];
        #pragma unroll
        for (int j = 0; j < 8; j++) {
            bf16x8 b = *(const bf16x8*)&Bp[(long)(j * 16 + l16) * 256 + kc * 32 + quad * 8];
            acc[j] = __builtin_amdgcn_mfma_f32_16x16x32_bf16(a, b, acc[j], 0, 0, 0);
        }
    }
    #pragma unroll
    for (int j = 0; j < 8; j++) {
        int col = j0 + j * 16 + l16;
        int which = col >> 8, h = (col >> 6) & 3, d = col & 63;
        u16* dst = (which == 0) ? Qo : (which == 1) ? Ko : Vo;
        #pragma unroll
        for (int r = 0; r < 4; r++) {
            int m = m0 + w * 16 + quad * 4 + r;
            int n = m >> 12, s = m & 4095;
            dst[((n * 4 + h) * SEQ + s) * 64 + d] = f2bf(acc[j][r]);
        }
    }
}

// ---------------------------------------------------------------------------
// Pass 1 (R2-proven): partial column sums D4[qc][nh][k] = sum_q exp(QK^T/64).
// ---------------------------------------------------------------------------
__global__ __launch_bounds__(256) void k_pass1(const u16* __restrict__ Q,
                                               const u16* __restrict__ Km,
                                               float* __restrict__ D4)
{
    __shared__ __align__(16) u16 lQ[128][72];
    int nh = blockIdx.y, k0 = blockIdx.x * 128, qc = blockIdx.z;
    const u16* Qh = Q + (long)nh * SEQ * 64;
    const u16* Kh = Km + (long)nh * SEQ * 64;
    int t = threadIdx.x, w = t >> 6, lane = t & 63, quad = lane >> 4, l16 = lane & 15;
    bf16x8 Kf[2][2];
    #pragma unroll
    for (int i = 0; i < 2; i++)
        #pragma unroll
        for (int ch = 0; ch < 2; ch++)
            Kf[i][ch] = *(const bf16x8*)&Kh[(k0 + w * 32 + i * 16 + l16) * 64 + ch * 32 + quad * 8];
    f32x4 z = {0.f, 0.f, 0.f, 0.f};
    float Dacc[2][4] = {{0.f, 0.f, 0.f, 0.f}, {0.f, 0.f, 0.f, 0.f}};
    const float C = 0.015625f * 1.44269504088896f;   // log2(e)/64
    for (int q0 = qc * 1024; q0 < qc * 1024 + 1024; q0 += 128) {
        #pragma unroll
        for (int p = 0; p < 4; p++) {
            int idx = t + p * 256;
            int row = idx >> 3, cc = (idx & 7) * 8;
            *(uint4*)&lQ[row][cc] = *(const uint4*)&Qh[(q0 + row) * 64 + cc];
        }
        __syncthreads();
        #pragma unroll
        for (int j = 0; j < 8; j++) {
            bf16x8 b0 = *(const bf16x8*)&lQ[j * 16 + l16][quad * 8];
            bf16x8 b1 = *(const bf16x8*)&lQ[j * 16 + l16][32 + quad * 8];
            #pragma unroll
            for (int i = 0; i < 2; i++) {
                f32x4 acc = z;
                acc = __builtin_amdgcn_mfma_f32_16x16x32_bf16(Kf[i][0], b0, acc, 0, 0, 0);
                acc = __builtin_amdgcn_mfma_f32_16x16x32_bf16(Kf[i][1], b1, acc, 0, 0, 0);
                #pragma unroll
                for (int r = 0; r < 4; r++) Dacc[i][r] += exp2f(acc[r] * C);
            }
        }
        __syncthreads();
    }
    #pragma unroll
    for (int i = 0; i < 2; i++)
        #pragma unroll
        for (int r = 0; r < 4; r++) {
            float v = Dacc[i][r];
            v += __shfl_xor(v, 1); v += __shfl_xor(v, 2);
            v += __shfl_xor(v, 4); v += __shfl_xor(v, 8);
            if (l16 == 0)
                D4[((long)(qc * NHT + nh)) * SEQ + k0 + w * 32 + i * 16 + quad * 4 + r] = v;
        }
}

// ---------------------------------------------------------------------------
// Scale+transpose V (R2-proven): Vt[nh][d][k] = V[nh][k][d] / D[nh][k].
// ---------------------------------------------------------------------------
__global__ __launch_bounds__(256) void k_scaleV(const u16* __restrict__ V,
                                                const float* __restrict__ D4,
                                                u16* __restrict__ Vt)
{
    __shared__ float tile[64][65];
    int nh = blockIdx.y, k0 = blockIdx.x * 64;
    int t = threadIdx.x;
    int d = t & 63, kk = t >> 6;
    const u16* Vh = V + (long)nh * SEQ * 64;
    for (int p = 0; p < 16; p++) {
        int k = p * 4 + kk;
        float Dv = D4[((long)(0 * NHT + nh)) * SEQ + k0 + k]
                 + D4[((long)(1 * NHT + nh)) * SEQ + k0 + k]
                 + D4[((long)(2 * NHT + nh)) * SEQ + k0 + k]
                 + D4[((long)(3 * NHT + nh)) * SEQ + k0 + k];
        tile[k][d] = bf2f(Vh[(k0 + k) * 64 + d]) * (1.f / Dv);
    }
    __syncthreads();
    int k2 = t & 63, d4 = t >> 6;
    u16* Vth = Vt + (long)nh * 64 * SEQ;
    for (int p = 0; p < 16; p++) {
        int dd = p * 4 + d4;
        Vth[dd * SEQ + k0 + k2] = f2bf(tile[k2][dd]);
    }
}

// ---------------------------------------------------------------------------
// Pass 2, WAVE-SPLIT-K (zero barriers in main loop). Block = (nh, 64 q,
// 2048-k chunk). Wave w owns k range [kbase + w*512, +512), stepping 32 k:
//   ST: S^T[32k x 64q] via 16 MFMAs; K-frags from global are DISTINCT per
//       wave (no redundant loads, unlike R5). exp -> packed uint2 into the
//       wave's PRIVATE lP strip [64 q][32 k] (within-wave lgkmcnt ordering,
//       no barrier; DS ops from one wave are in-order so no WAR on reuse).
//   PV: A-frags from own lP (b128), B V'-frags from global (distinct per
//       wave), accumulate full 64q x 64d in registers (accO[4][4]).
// End: 4-barrier sequential LDS reduction of the 4 wave partials (red
// overlays lP), then coalesced store of this chunk's partial to acat2.
// Registers (~140) intentionally high: room for in-flight next-step loads.
// Grid (64 q-tiles, 8 nh, 2 k-chunks).
// ---------------------------------------------------------------------------
__global__ __launch_bounds__(256) void k_pass2(const u16* __restrict__ Q,
                                               const u16* __restrict__ Km,
                                               const u16* __restrict__ Vt,
                                               float* __restrict__ acat2)
{
    __shared__ __align__(16) unsigned char smem[4 * 64 * 36 * 2];  // 18432 B
    u16 (*lP)[64][36] = (u16(*)[64][36])smem;       // per-wave strips
    float (*red)[65] = (float(*)[65])smem;          // 64*65*4 = 16640 B overlay

    int nh = blockIdx.y, q0 = blockIdx.x * 64, kcid = blockIdx.z;
    int n = nh >> 2, h = nh & 3;
    const u16* Qh = Q + (long)nh * SEQ * 64;
    const u16* Kh = Km + (long)nh * SEQ * 64;
    const u16* Vh = Vt + (long)nh * 64 * SEQ;
    int t = threadIdx.x, w = t >> 6, lane = t & 63, quad = lane >> 4, l16 = lane & 15;
    // Q fragments for the full 64-q tile (shared dims; loaded per wave)
    bf16x8 Qf[4][2];
    #pragma unroll
    for (int jq = 0; jq < 4; jq++)
        #pragma unroll
        for (int ch = 0; ch < 2; ch++)
            Qf[jq][ch] = *(const bf16x8*)&Qh[(q0 + jq * 16 + l16) * 64 + ch * 32 + quad * 8];
    f32x4 z = {0.f, 0.f, 0.f, 0.f};
    f32x4 accO[4][4];
    #pragma unroll
    for (int jq = 0; jq < 4; jq++)
        #pragma unroll
        for (int jd = 0; jd < 4; jd++) accO[jq][jd] = z;
    const float C = 0.015625f * 1.44269504088896f;   // log2(e)/64

    const int kw0 = kcid * 2048 + w * 512;
    for (int step = 0; step < 16; step++) {
        int k0 = kw0 + step * 32;
        // ST: 32 k x 64 q for this wave's window
        #pragma unroll
        for (int ksub = 0; ksub < 2; ksub++) {
            bf16x8 a0 = *(const bf16x8*)&Kh[(k0 + ksub * 16 + l16) * 64 + quad * 8];
            bf16x8 a1 = *(const bf16x8*)&Kh[(k0 + ksub * 16 + l16) * 64 + 32 + quad * 8];
            #pragma unroll
            for (int jq = 0; jq < 4; jq++) {
                f32x4 acc = z;
                acc = __builtin_amdgcn_mfma_f32_16x16x32_bf16(a0, Qf[jq][0], acc, 0, 0, 0);
                acc = __builtin_amdgcn_mfma_f32_16x16x32_bf16(a1, Qf[jq][1], acc, 0, 0, 0);
                u32 e0 = __float_as_uint(exp2f(acc[0] * C));
                u32 e1 = __float_as_uint(exp2f(acc[1] * C));
                u32 e2 = __float_as_uint(exp2f(acc[2] * C));
                u32 e3 = __float_as_uint(exp2f(acc[3] * C));
                uint2 pk;
                pk.x = ((e0 + 0x8000u) >> 16) | ((e1 + 0x8000u) & 0xffff0000u);
                pk.y = ((e2 + 0x8000u) >> 16) | ((e3 + 0x8000u) & 0xffff0000u);
                *(uint2*)&lP[w][jq * 16 + l16][ksub * 16 + quad * 4] = pk;
            }
        }
        // PV: own 32-k window x 64 d, A from own lP strip
        #pragma unroll
        for (int jq = 0; jq < 4; jq++) {
            bf16x8 pa = *(const bf16x8*)&lP[w][jq * 16 + l16][quad * 8];
            #pragma unroll
            for (int jd = 0; jd < 4; jd++) {
                bf16x8 vb = *(const bf16x8*)&Vh[(jd * 16 + l16) * SEQ + k0 + quad * 8];
                accO[jq][jd] = __builtin_amdgcn_mfma_f32_16x16x32_bf16(pa, vb, accO[jq][jd], 0, 0, 0);
            }
        }
    }
    // cross-wave reduction: sequential accumulate into red (overlays lP)
    __syncthreads();
    for (int src = 0; src < 4; src++) {
        if (w == src) {
            #pragma unroll
            for (int jq = 0; jq < 4; jq++)
                #pragma unroll
                for (int jd = 0; jd < 4; jd++)
                    #pragma unroll
                    for (int r = 0; r < 4; r++) {
                        float* cell = &red[jq * 16 + quad * 4 + r][jd * 16 + l16];
                        if (src == 0) *cell = accO[jq][jd][r];
                        else          *cell += accO[jq][jd][r];
                    }
        }
        __syncthreads();
    }
    float* dst = acat2 + (long)kcid * 8192 * 256;
    for (int qq = 0; qq < 16; qq++) {
        int s = q0 + w * 16 + qq;
        dst[((long)n * SEQ + s) * 256 + h * 64 + lane] = red[w * 16 + qq][lane];
    }
}

// ---------------------------------------------------------------------------
// LN2 + partial-sum fold: reads 2 pass-2 partials, writes summed acat (for
// mlp2 residual) and h2 = LN(x^T + acat) bf16.
// ---------------------------------------------------------------------------
__global__ __launch_bounds__(256) void k_ln2(const float* __restrict__ x,
                                             const float* __restrict__ acat2,
                                             const float* __restrict__ w,
                                             const float* __restrict__ b,
                                             u16* __restrict__ h2,
                                             float* __restrict__ acat)
{
    __shared__ float tile[32][257];
    __shared__ float mu[32], rs[32];
    int n = blockIdx.y, s0 = blockIdx.x * 32;
    int t = threadIdx.x;
    int sl = t & 31, cg = t >> 5;
    for (int cc = 0; cc < 256; cc += 8) {
        int c = cc + cg;
        tile[sl][c] = x[(n * 256 + c) * SEQ + s0 + sl];
    }
    __syncthreads();
    const long STRIDE = (long)8192 * 256;
    for (int s = 0; s < 32; s++) {
        long idx = ((long)n * SEQ + s0 + s) * 256 + t;
        float a = acat2[idx] + acat2[idx + STRIDE];
        acat[idx] = a;
        tile[s][t] += a;
    }
    __syncthreads();
    int wv = t >> 6, l = t & 63;
    for (int rr = 0; rr < 8; rr++) {
        int s = wv * 8 + rr;
        float a0 = tile[s][l], a1 = tile[s][l + 64], a2 = tile[s][l + 128], a3 = tile[s][l + 192];
        float sm = a0 + a1 + a2 + a3;
        float sq = a0 * a0 + a1 * a1 + a2 * a2 + a3 * a3;
        for (int off = 32; off; off >>= 1) { sm += __shfl_xor(sm, off); sq += __shfl_xor(sq, off); }
        if (l == 0) {
            float m = sm * (1.f / 256.f);
            mu[s] = m;
            rs[s] = rsqrtf(sq * (1.f / 256.f) - m * m + 1e-5f);
        }
    }
    __syncthreads();
    float ww = w[t], bb = b[t];
    for (int s = 0; s < 32; s++) {
        float v = (tile[s][t] - mu[s]) * rs[s] * ww + bb;
        h2[((long)n * SEQ + s0 + s) * 256 + t] = f2bf(v);
    }
}

// ---------------------------------------------------------------------------
// MLP1, barrier-free (R4-proven).
// ---------------------------------------------------------------------------
__global__ __launch_bounds__(256) void k_mlp1(const u16* __restrict__ h2,
                                              const u16* __restrict__ W1t,
                                              const float* __restrict__ b1,
                                              u16* __restrict__ tbuf)
{
    int m0 = blockIdx.x * 64, j0 = blockIdx.y * 128;
    int t = threadIdx.x, w = t >> 6, lane = t & 63, quad = lane >> 4, l16 = lane & 15;
    const u16* Ap = h2 + (long)(m0 + w * 16 + l16) * 256;
    const u16* Bp = W1t + (long)j0 * 256;
    f32x4 z = {0.f, 0.f, 0.f, 0.f};
    f32x4 acc[8];
    #pragma unroll
    for (int j = 0; j < 8; j++) acc[j] = z;
    #pragma unroll
    for (int kc = 0; kc < 8; kc++) {
        bf16x8 a = *(const bf16x8*)&Ap[kc * 32 + quad * 8];
        #pragma unroll
        for (int j = 0; j < 8; j++) {
            bf16x8 b = *(const bf16x8*)&Bp[(long)(j * 16 + l16) * 256 + kc * 32 + quad * 8];
            acc[j] = __builtin_amdgcn_mfma_f32_16x16x32_bf16(a, b, acc[j], 0, 0, 0);
        }
    }
    #pragma unroll
    for (int j = 0; j < 8; j++) {
        int col = j0 + j * 16 + l16;
        float bj = b1[col];
        #pragma unroll
        for (int r = 0; r < 4; r++) {
            int m = m0 + w * 16 + quad * 4 + r;
            float v = acc[j][r] + bj;
            float g = 0.5f * v * (1.f + erff(v * 0.70710678118f));
            tbuf[(long)m * 256 + col] = f2bf(g);
        }
    }
}

// ---------------------------------------------------------------------------
// MLP2 + residual + fused output transpose (R4-proven).
// ---------------------------------------------------------------------------
__global__ __launch_bounds__(256) void k_mlp2(const u16* __restrict__ tbuf,
                                              const u16* __restrict__ W2t,
                                              const float* __restrict__ b2,
                                              const float* __restrict__ acat,
                                              float* __restrict__ out)
{
    __shared__ float LT[128][68];
    int m0 = blockIdx.x * 64, j0 = blockIdx.y * 128;
    int t = threadIdx.x, w = t >> 6, lane = t & 63, quad = lane >> 4, l16 = lane & 15;
    const u16* Ap = tbuf + (long)(m0 + w * 16 + l16) * 256;
    const u16* Bp = W2t + (long)j0 * 256;
    f32x4 z = {0.f, 0.f, 0.f, 0.f};
    f32x4 acc[8];
    #pragma unroll
    for (int j = 0; j < 8; j++) acc[j] = z;
    #pragma unroll
    for (int kc = 0; kc < 8; kc++) {
        bf16x8 a = *(const bf16x8*)&Ap[kc * 32 + quad * 8];
        #pragma unroll
        for (int j = 0; j < 8; j++) {
            bf16x8 b = *(const bf16x8*)&Bp[(long)(j * 16 + l16) * 256 + kc * 32 + quad * 8];
            acc[j] = __builtin_amdgcn_mfma_f32_16x16x32_bf16(a, b, acc[j], 0, 0, 0);
        }
    }
    #pragma unroll
    for (int j = 0; j < 8; j++) {
        int col = j0 + j * 16 + l16;
        float bj = b2[col];
        #pragma unroll
        for (int r = 0; r < 4; r++) {
            int m = m0 + w * 16 + quad * 4 + r;
            float v = acc[j][r] + bj + acat[(long)m * 256 + col];
            LT[j * 16 + l16][w * 16 + quad * 4 + r] = v;
        }
    }
    __syncthreads();
    int n = m0 >> 12, sbase = m0 & 4095;
    #pragma unroll
    for (int p = 0; p < 8; p++) {
        int row = p * 16 + (t >> 4);
        int ch = (t & 15) * 4;
        float4 v = *(float4*)&LT[row][ch];
        *(float4*)&out[((long)n * 256 + j0 + row) * SEQ + sbase + ch] = v;
    }
}

// ---------------------------------------------------------------------------
extern "C" void kernel_launch(void* const* d_in, const int* in_sizes, int n_in,
                              void* d_out, int out_size, void* d_ws, size_t ws_size,
                              hipStream_t stream) {
    const float* x    = (const float*)d_in[0];
    const float* ln1w = (const float*)d_in[1];
    const float* ln1b = (const float*)d_in[2];
    const float* WQ   = (const float*)d_in[3];
    const float* WK   = (const float*)d_in[4];
    const float* WV   = (const float*)d_in[5];
    const float* ln2w = (const float*)d_in[6];
    const float* ln2b = (const float*)d_in[7];
    const float* W1   = (const float*)d_in[8];
    const float* b1   = (const float*)d_in[9];
    const float* W2   = (const float*)d_in[10];
    const float* b2   = (const float*)d_in[11];
    float* out = (float*)d_out;

    char* p = (char*)d_ws;
    u16* norm   = (u16*)p;   p += (size_t)8192 * 256 * 2;
    u16* BtQKV  = (u16*)p;   p += (size_t)768 * 256 * 2;
    u16* W1t    = (u16*)p;   p += (size_t)256 * 256 * 2;
    u16* W2t    = (u16*)p;   p += (size_t)256 * 256 * 2;
    u16* Qb     = (u16*)p;   p += (size_t)NHT * SEQ * 64 * 2;
    u16* Kb     = (u16*)p;   p += (size_t)NHT * SEQ * 64 * 2;
    u16* Vb     = (u16*)p;   p += (size_t)NHT * SEQ * 64 * 2;
    float* D4   = (float*)p; p += (size_t)4 * NHT * SEQ * 4;
    u16* Vt     = (u16*)p;   p += (size_t)NHT * SEQ * 64 * 2;
    float* acat2= (float*)p; p += (size_t)2 * 8192 * 256 * 4;
    float* acat = (float*)p; p += (size_t)8192 * 256 * 4;
    u16* h2     = (u16*)p;   p += (size_t)8192 * 256 * 2;
    u16* tbuf   = (u16*)p;   p += (size_t)8192 * 256 * 2;

    k_pack<<<1280, 256, 0, stream>>>(WQ, WK, WV, W1, W2, BtQKV, W1t, W2t);
    k_ln1<<<dim3(128, 2), 256, 0, stream>>>(x, ln1w, ln1b, norm);
    k_qkv<<<dim3(128, 6), 256, 0, stream>>>(norm, BtQKV, Qb, Kb, Vb);
    k_pass1<<<dim3(32, 8, 4), 256, 0, stream>>>(Qb, Kb, D4);
    k_scaleV<<<dim3(64, 8), 256, 0, stream>>>(Vb, D4, Vt);
    k_pass2<<<dim3(64, 8, 2), 256, 0, stream>>>(Qb, Kb, Vt, acat2);
    k_ln2<<<dim3(128, 2), 256, 0, stream>>>(x, acat2, ln2w, ln2b, h2, acat);
    k_mlp1<<<dim3(128, 2), 256, 0, stream>>>(h2, W1t, b1, tbuf);
    k_mlp2<<<dim3(128, 2), 256, 0, stream>>>(tbuf, W2t, b2, acat, out);
}

// Round 7
// 288.086 us; speedup vs baseline: 1.5693x; 1.0829x over previous
//
#include <hip/hip_runtime.h>
#include <math.h>

#define SEQ 4096
#define CH  256
#define NHT 8      // N * HEADS
#define DHD 64

// Q is pre-scaled by log2(e)/64 at projection time, so both attention passes
// compute exp2(S) with zero multiplies.
#define QSCALE 0.0225421092f

using bf16x8 = __attribute__((ext_vector_type(8))) short;
using f32x4  = __attribute__((ext_vector_type(4))) float;
typedef unsigned short u16;
typedef unsigned int   u32;

__device__ __forceinline__ u16 f2bf(float f) {
    u32 u = __float_as_uint(f);
    u = (u + 0x7fffu + ((u >> 16) & 1u)) >> 16;
    return (u16)u;
}
__device__ __forceinline__ float bf2f(u16 h) {
    return __uint_as_float(((u32)h) << 16);
}

// ---------------------------------------------------------------------------
// Weight pack (transposed for NT GEMM).
// ---------------------------------------------------------------------------
__global__ __launch_bounds__(256) void k_pack(const float* __restrict__ WQ,
                                              const float* __restrict__ WK,
                                              const float* __restrict__ WV,
                                              const float* __restrict__ W1,
                                              const float* __restrict__ W2,
                                              u16* __restrict__ BtQKV,
                                              u16* __restrict__ W1t,
                                              u16* __restrict__ W2t)
{
    int id = blockIdx.x * 256 + threadIdx.x;
    if (id < 768 * 256) {
        int j = id >> 8, c = id & 255;
        int which = j >> 8, h = (j >> 6) & 3, d = j & 63;
        const float* W = (which == 0) ? WQ : (which == 1) ? WK : WV;
        BtQKV[id] = f2bf(W[(h * 256 + c) * 64 + d]);
    } else if (id < 768 * 256 + 65536) {
        int jj = id - 768 * 256;
        int j = jj >> 8, c = jj & 255;
        W1t[jj] = f2bf(W1[c * 256 + j]);
    } else if (id < 768 * 256 + 2 * 65536) {
        int jj = id - 768 * 256 - 65536;
        int j = jj >> 8, c = jj & 255;
        W2t[jj] = f2bf(W2[c * 256 + j]);
    }
}

// ---------------------------------------------------------------------------
// LN1 (R2-proven): x [N][C][S] -> norm bf16 [N][S][C]. 32 s-rows per block.
// ---------------------------------------------------------------------------
__global__ __launch_bounds__(256) void k_ln1(const float* __restrict__ x,
                                             const float* __restrict__ w,
                                             const float* __restrict__ b,
                                             u16* __restrict__ norm)
{
    __shared__ float tile[32][257];
    __shared__ float mu[32], rs[32];
    int n = blockIdx.y, s0 = blockIdx.x * 32;
    int t = threadIdx.x;
    int sl = t & 31, cg = t >> 5;
    for (int cc = 0; cc < 256; cc += 8) {
        int c = cc + cg;
        tile[sl][c] = x[(n * 256 + c) * SEQ + s0 + sl];
    }
    __syncthreads();
    int wv = t >> 6, l = t & 63;
    for (int rr = 0; rr < 8; rr++) {
        int s = wv * 8 + rr;
        float a0 = tile[s][l], a1 = tile[s][l + 64], a2 = tile[s][l + 128], a3 = tile[s][l + 192];
        float sm = a0 + a1 + a2 + a3;
        float sq = a0 * a0 + a1 * a1 + a2 * a2 + a3 * a3;
        for (int off = 32; off; off >>= 1) { sm += __shfl_xor(sm, off); sq += __shfl_xor(sq, off); }
        if (l == 0) {
            float m = sm * (1.f / 256.f);
            mu[s] = m;
            rs[s] = rsqrtf(sq * (1.f / 256.f) - m * m + 1e-5f);
        }
    }
    __syncthreads();
    float ww = w[t & 255], bb = b[t & 255];
    for (int s = 0; s < 32; s++) {
        float v = (tile[s][t] - mu[s]) * rs[s] * ww + bb;
        norm[(n * SEQ + s0 + s) * 256 + t] = f2bf(v);
    }
}

// ---------------------------------------------------------------------------
// QKV projection, barrier-free (R4-proven). Q outputs pre-scaled by QSCALE.
// ---------------------------------------------------------------------------
__global__ __launch_bounds__(256) void k_qkv(const u16* __restrict__ norm,
                                             const u16* __restrict__ Bt,
                                             u16* __restrict__ Qo,
                                             u16* __restrict__ Ko,
                                             u16* __restrict__ Vo)
{
    int m0 = blockIdx.x * 64, j0 = blockIdx.y * 128;
    int t = threadIdx.x, w = t >> 6, lane = t & 63, quad = lane >> 4, l16 = lane & 15;
    const u16* Ap = norm + (long)(m0 + w * 16 + l16) * 256;
    const u16* Bp = Bt + (long)j0 * 256;
    f32x4 z = {0.f, 0.f, 0.f, 0.f};
    f32x4 acc[8];
    #pragma unroll
    for (int j = 0; j < 8; j++) acc[j] = z;
    #pragma unroll
    for (int kc = 0; kc < 8; kc++) {
        bf16x8 a = *(const bf16x8*)&Ap[kc * 32 + quad * 8];
        #pragma unroll
        for (int j = 0; j < 8; j++) {
            bf16x8 b = *(const bf16x8*)&Bp[(long)(j * 16 + l16) * 256 + kc * 32 + quad * 8];
            acc[j] = __builtin_amdgcn_mfma_f32_16x16x32_bf16(a, b, acc[j], 0, 0, 0);
        }
    }
    #pragma unroll
    for (int j = 0; j < 8; j++) {
        int col = j0 + j * 16 + l16;
        int which = col >> 8, h = (col >> 6) & 3, d = col & 63;
        u16* dst = (which == 0) ? Qo : (which == 1) ? Ko : Vo;
        float sc = (which == 0) ? QSCALE : 1.0f;
        #pragma unroll
        for (int r = 0; r < 4; r++) {
            int m = m0 + w * 16 + quad * 4 + r;
            int n = m >> 12, s = m & 4095;
            dst[((n * 4 + h) * SEQ + s) * 64 + d] = f2bf(acc[j][r] * sc);
        }
    }
}

// ---------------------------------------------------------------------------
// Pass 1 (R2-proven structure): partial column sums D4[qc][nh][k] =
// sum_q exp2(Q_scaled·K^T). No multiply in the exp chain (Q pre-scaled).
// ---------------------------------------------------------------------------
__global__ __launch_bounds__(256) void k_pass1(const u16* __restrict__ Q,
                                               const u16* __restrict__ Km,
                                               float* __restrict__ D4)
{
    __shared__ __align__(16) u16 lQ[128][72];
    int nh = blockIdx.y, k0 = blockIdx.x * 128, qc = blockIdx.z;
    const u16* Qh = Q + (long)nh * SEQ * 64;
    const u16* Kh = Km + (long)nh * SEQ * 64;
    int t = threadIdx.x, w = t >> 6, lane = t & 63, quad = lane >> 4, l16 = lane & 15;
    bf16x8 Kf[2][2];
    #pragma unroll
    for (int i = 0; i < 2; i++)
        #pragma unroll
        for (int ch = 0; ch < 2; ch++)
            Kf[i][ch] = *(const bf16x8*)&Kh[(k0 + w * 32 + i * 16 + l16) * 64 + ch * 32 + quad * 8];
    f32x4 z = {0.f, 0.f, 0.f, 0.f};
    float Dacc[2][4] = {{0.f, 0.f, 0.f, 0.f}, {0.f, 0.f, 0.f, 0.f}};
    for (int q0 = qc * 1024; q0 < qc * 1024 + 1024; q0 += 128) {
        #pragma unroll
        for (int p = 0; p < 4; p++) {
            int idx = t + p * 256;
            int row = idx >> 3, cc = (idx & 7) * 8;
            *(uint4*)&lQ[row][cc] = *(const uint4*)&Qh[(q0 + row) * 64 + cc];
        }
        __syncthreads();
        #pragma unroll
        for (int j = 0; j < 8; j++) {
            bf16x8 b0 = *(const bf16x8*)&lQ[j * 16 + l16][quad * 8];
            bf16x8 b1 = *(const bf16x8*)&lQ[j * 16 + l16][32 + quad * 8];
            #pragma unroll
            for (int i = 0; i < 2; i++) {
                f32x4 acc = z;
                acc = __builtin_amdgcn_mfma_f32_16x16x32_bf16(Kf[i][0], b0, acc, 0, 0, 0);
                acc = __builtin_amdgcn_mfma_f32_16x16x32_bf16(Kf[i][1], b1, acc, 0, 0, 0);
                #pragma unroll
                for (int r = 0; r < 4; r++) Dacc[i][r] += exp2f(acc[r]);
            }
        }
        __syncthreads();
    }
    #pragma unroll
    for (int i = 0; i < 2; i++)
        #pragma unroll
        for (int r = 0; r < 4; r++) {
            float v = Dacc[i][r];
            v += __shfl_xor(v, 1); v += __shfl_xor(v, 2);
            v += __shfl_xor(v, 4); v += __shfl_xor(v, 8);
            if (l16 == 0)
                D4[((long)(qc * NHT + nh)) * SEQ + k0 + w * 32 + i * 16 + quad * 4 + r] = v;
        }
}

// ---------------------------------------------------------------------------
// Scale+transpose V (R2-proven): Vt[nh][d][k] = V[nh][k][d] / D[nh][k].
// ---------------------------------------------------------------------------
__global__ __launch_bounds__(256) void k_scaleV(const u16* __restrict__ V,
                                                const float* __restrict__ D4,
                                                u16* __restrict__ Vt)
{
    __shared__ float tile[64][65];
    int nh = blockIdx.y, k0 = blockIdx.x * 64;
    int t = threadIdx.x;
    int d = t & 63, kk = t >> 6;
    const u16* Vh = V + (long)nh * SEQ * 64;
    for (int p = 0; p < 16; p++) {
        int k = p * 4 + kk;
        float Dv = D4[((long)(0 * NHT + nh)) * SEQ + k0 + k]
                 + D4[((long)(1 * NHT + nh)) * SEQ + k0 + k]
                 + D4[((long)(2 * NHT + nh)) * SEQ + k0 + k]
                 + D4[((long)(3 * NHT + nh)) * SEQ + k0 + k];
        tile[k][d] = bf2f(Vh[(k0 + k) * 64 + d]) * (1.f / Dv);
    }
    __syncthreads();
    int k2 = t & 63, d4 = t >> 6;
    u16* Vth = Vt + (long)nh * 64 * SEQ;
    for (int p = 0; p < 16; p++) {
        int dd = p * 4 + d4;
        Vth[dd * SEQ + k0 + k2] = f2bf(tile[k2][dd]);
    }
}

// ---------------------------------------------------------------------------
// Pass 2, wave-split-k (R6-proven) + R7 deltas:
//  - K-frag software pipeline (prefetch next step's 4 frags)
//  - exp2 with no multiply (Q pre-scaled), v_perm-based bf16 pack
//  - 2-strip LDS reduction (3 barriers) + float4 coalesced partial store
// Grid (64 q-tiles, 8 nh, 2 k-chunks).
// ---------------------------------------------------------------------------
__global__ __launch_bounds__(256) void k_pass2(const u16* __restrict__ Q,
                                               const u16* __restrict__ Km,
                                               const u16* __restrict__ Vt,
                                               float* __restrict__ acat2)
{
    __shared__ __align__(16) unsigned char smem[34816];
    u16 (*lP)[64][36] = (u16(*)[64][36])smem;               // 4 strips, 18432 B
    float (*SA)[68] = (float(*)[68])smem;                   // 17408 B
    float (*SB)[68] = (float(*)[68])(smem + 17408);         // 17408 B

    int nh = blockIdx.y, q0 = blockIdx.x * 64, kcid = blockIdx.z;
    int n = nh >> 2, h = nh & 3;
    const u16* Qh = Q + (long)nh * SEQ * 64;
    const u16* Kh = Km + (long)nh * SEQ * 64;
    const u16* Vh = Vt + (long)nh * 64 * SEQ;
    int t = threadIdx.x, w = t >> 6, lane = t & 63, quad = lane >> 4, l16 = lane & 15;
    bf16x8 Qf[4][2];
    #pragma unroll
    for (int jq = 0; jq < 4; jq++)
        #pragma unroll
        for (int ch = 0; ch < 2; ch++)
            Qf[jq][ch] = *(const bf16x8*)&Qh[(q0 + jq * 16 + l16) * 64 + ch * 32 + quad * 8];
    f32x4 z = {0.f, 0.f, 0.f, 0.f};
    f32x4 accO[4][4];
    #pragma unroll
    for (int jq = 0; jq < 4; jq++)
        #pragma unroll
        for (int jd = 0; jd < 4; jd++) accO[jq][jd] = z;

    const int kw0 = kcid * 2048 + w * 512;
    bf16x8 kA[2][2], nA[2][2];
    #pragma unroll
    for (int ksub = 0; ksub < 2; ksub++) {
        kA[ksub][0] = *(const bf16x8*)&Kh[(kw0 + ksub * 16 + l16) * 64 + quad * 8];
        kA[ksub][1] = *(const bf16x8*)&Kh[(kw0 + ksub * 16 + l16) * 64 + 32 + quad * 8];
    }
    for (int step = 0; step < 16; step++) {
        int k0 = kw0 + step * 32;
        if (step < 15) {
            #pragma unroll
            for (int ksub = 0; ksub < 2; ksub++) {
                nA[ksub][0] = *(const bf16x8*)&Kh[(k0 + 32 + ksub * 16 + l16) * 64 + quad * 8];
                nA[ksub][1] = *(const bf16x8*)&Kh[(k0 + 32 + ksub * 16 + l16) * 64 + 32 + quad * 8];
            }
        }
        // ST: 32 k x 64 q for this wave's window
        #pragma unroll
        for (int ksub = 0; ksub < 2; ksub++) {
            #pragma unroll
            for (int jq = 0; jq < 4; jq++) {
                f32x4 acc = z;
                acc = __builtin_amdgcn_mfma_f32_16x16x32_bf16(kA[ksub][0], Qf[jq][0], acc, 0, 0, 0);
                acc = __builtin_amdgcn_mfma_f32_16x16x32_bf16(kA[ksub][1], Qf[jq][1], acc, 0, 0, 0);
                u32 e0 = __float_as_uint(exp2f(acc[0])) + 0x8000u;
                u32 e1 = __float_as_uint(exp2f(acc[1])) + 0x8000u;
                u32 e2 = __float_as_uint(exp2f(acc[2])) + 0x8000u;
                u32 e3 = __float_as_uint(exp2f(acc[3])) + 0x8000u;
                uint2 pk;
                pk.x = __builtin_amdgcn_perm(e1, e0, 0x07060302u);
                pk.y = __builtin_amdgcn_perm(e3, e2, 0x07060302u);
                *(uint2*)&lP[w][jq * 16 + l16][ksub * 16 + quad * 4] = pk;
            }
        }
        // PV: own 32-k window x 64 d
        #pragma unroll
        for (int jq = 0; jq < 4; jq++) {
            bf16x8 pa = *(const bf16x8*)&lP[w][jq * 16 + l16][quad * 8];
            #pragma unroll
            for (int jd = 0; jd < 4; jd++) {
                bf16x8 vb = *(const bf16x8*)&Vh[(jd * 16 + l16) * SEQ + k0 + quad * 8];
                accO[jq][jd] = __builtin_amdgcn_mfma_f32_16x16x32_bf16(pa, vb, accO[jq][jd], 0, 0, 0);
            }
        }
        #pragma unroll
        for (int ksub = 0; ksub < 2; ksub++) {
            kA[ksub][0] = nA[ksub][0];
            kA[ksub][1] = nA[ksub][1];
        }
    }
    // 2-strip reduction: waves 2,3 deposit; waves 0,1 add+redeposit; all store.
    __syncthreads();
    if (w >= 2) {
        float (*S)[68] = (w == 2) ? SA : SB;
        #pragma unroll
        for (int jq = 0; jq < 4; jq++)
            #pragma unroll
            for (int jd = 0; jd < 4; jd++)
                #pragma unroll
                for (int r = 0; r < 4; r++)
                    S[jq * 16 + quad * 4 + r][jd * 16 + l16] = accO[jq][jd][r];
    }
    __syncthreads();
    if (w < 2) {
        float (*S)[68] = (w == 0) ? SA : SB;
        #pragma unroll
        for (int jq = 0; jq < 4; jq++)
            #pragma unroll
            for (int jd = 0; jd < 4; jd++)
                #pragma unroll
                for (int r = 0; r < 4; r++) {
                    float v = accO[jq][jd][r] + S[jq * 16 + quad * 4 + r][jd * 16 + l16];
                    S[jq * 16 + quad * 4 + r][jd * 16 + l16] = v;
                }
    }
    __syncthreads();
    float* dst = acat2 + (long)kcid * 8192 * 256;
    #pragma unroll
    for (int p = 0; p < 4; p++) {
        int row = p * 16 + (t >> 4);
        int ch = (t & 15) * 4;
        float4 va = *(float4*)&SA[row][ch];
        float4 vb = *(float4*)&SB[row][ch];
        float4 o = make_float4(va.x + vb.x, va.y + vb.y, va.z + vb.z, va.w + vb.w);
        *(float4*)&dst[((long)n * SEQ + q0 + row) * 256 + h * 64 + ch] = o;
    }
}

// ---------------------------------------------------------------------------
// LN2 + partial-sum fold (R6-proven).
// ---------------------------------------------------------------------------
__global__ __launch_bounds__(256) void k_ln2(const float* __restrict__ x,
                                             const float* __restrict__ acat2,
                                             const float* __restrict__ w,
                                             const float* __restrict__ b,
                                             u16* __restrict__ h2,
                                             float* __restrict__ acat)
{
    __shared__ float tile[32][257];
    __shared__ float mu[32], rs[32];
    int n = blockIdx.y, s0 = blockIdx.x * 32;
    int t = threadIdx.x;
    int sl = t & 31, cg = t >> 5;
    for (int cc = 0; cc < 256; cc += 8) {
        int c = cc + cg;
        tile[sl][c] = x[(n * 256 + c) * SEQ + s0 + sl];
    }
    __syncthreads();
    const long STRIDE = (long)8192 * 256;
    for (int s = 0; s < 32; s++) {
        long idx = ((long)n * SEQ + s0 + s) * 256 + t;
        float a = acat2[idx] + acat2[idx + STRIDE];
        acat[idx] = a;
        tile[s][t] += a;
    }
    __syncthreads();
    int wv = t >> 6, l = t & 63;
    for (int rr = 0; rr < 8; rr++) {
        int s = wv * 8 + rr;
        float a0 = tile[s][l], a1 = tile[s][l + 64], a2 = tile[s][l + 128], a3 = tile[s][l + 192];
        float sm = a0 + a1 + a2 + a3;
        float sq = a0 * a0 + a1 * a1 + a2 * a2 + a3 * a3;
        for (int off = 32; off; off >>= 1) { sm += __shfl_xor(sm, off); sq += __shfl_xor(sq, off); }
        if (l == 0) {
            float m = sm * (1.f / 256.f);
            mu[s] = m;
            rs[s] = rsqrtf(sq * (1.f / 256.f) - m * m + 1e-5f);
        }
    }
    __syncthreads();
    float ww = w[t], bb = b[t];
    for (int s = 0; s < 32; s++) {
        float v = (tile[s][t] - mu[s]) * rs[s] * ww + bb;
        h2[((long)n * SEQ + s0 + s) * 256 + t] = f2bf(v);
    }
}

// ---------------------------------------------------------------------------
// MLP1, barrier-free (R4-proven).
// ---------------------------------------------------------------------------
__global__ __launch_bounds__(256) void k_mlp1(const u16* __restrict__ h2,
                                              const u16* __restrict__ W1t,
                                              const float* __restrict__ b1,
                                              u16* __restrict__ tbuf)
{
    int m0 = blockIdx.x * 64, j0 = blockIdx.y * 128;
    int t = threadIdx.x, w = t >> 6, lane = t & 63, quad = lane >> 4, l16 = lane & 15;
    const u16* Ap = h2 + (long)(m0 + w * 16 + l16) * 256;
    const u16* Bp = W1t + (long)j0 * 256;
    f32x4 z = {0.f, 0.f, 0.f, 0.f};
    f32x4 acc[8];
    #pragma unroll
    for (int j = 0; j < 8; j++) acc[j] = z;
    #pragma unroll
    for (int kc = 0; kc < 8; kc++) {
        bf16x8 a = *(const bf16x8*)&Ap[kc * 32 + quad * 8];
        #pragma unroll
        for (int j = 0; j < 8; j++) {
            bf16x8 b = *(const bf16x8*)&Bp[(long)(j * 16 + l16) * 256 + kc * 32 + quad * 8];
            acc[j] = __builtin_amdgcn_mfma_f32_16x16x32_bf16(a, b, acc[j], 0, 0, 0);
        }
    }
    #pragma unroll
    for (int j = 0; j < 8; j++) {
        int col = j0 + j * 16 + l16;
        float bj = b1[col];
        #pragma unroll
        for (int r = 0; r < 4; r++) {
            int m = m0 + w * 16 + quad * 4 + r;
            float v = acc[j][r] + bj;
            float g = 0.5f * v * (1.f + erff(v * 0.70710678118f));
            tbuf[(long)m * 256 + col] = f2bf(g);
        }
    }
}

// ---------------------------------------------------------------------------
// MLP2 + residual + fused output transpose (R4-proven).
// ---------------------------------------------------------------------------
__global__ __launch_bounds__(256) void k_mlp2(const u16* __restrict__ tbuf,
                                              const u16* __restrict__ W2t,
                                              const float* __restrict__ b2,
                                              const float* __restrict__ acat,
                                              float* __restrict__ out)
{
    __shared__ float LT[128][68];
    int m0 = blockIdx.x * 64, j0 = blockIdx.y * 128;
    int t = threadIdx.x, w = t >> 6, lane = t & 63, quad = lane >> 4, l16 = lane & 15;
    const u16* Ap = tbuf + (long)(m0 + w * 16 + l16) * 256;
    const u16* Bp = W2t + (long)j0 * 256;
    f32x4 z = {0.f, 0.f, 0.f, 0.f};
    f32x4 acc[8];
    #pragma unroll
    for (int j = 0; j < 8; j++) acc[j] = z;
    #pragma unroll
    for (int kc = 0; kc < 8; kc++) {
        bf16x8 a = *(const bf16x8*)&Ap[kc * 32 + quad * 8];
        #pragma unroll
        for (int j = 0; j < 8; j++) {
            bf16x8 b = *(const bf16x8*)&Bp[(long)(j * 16 + l16) * 256 + kc * 32 + quad * 8];
            acc[j] = __builtin_amdgcn_mfma_f32_16x16x32_bf16(a, b, acc[j], 0, 0, 0);
        }
    }
    #pragma unroll
    for (int j = 0; j < 8; j++) {
        int col = j0 + j * 16 + l16;
        float bj = b2[col];
        #pragma unroll
        for (int r = 0; r < 4; r++) {
            int m = m0 + w * 16 + quad * 4 + r;
            float v = acc[j][r] + bj + acat[(long)m * 256 + col];
            LT[j * 16 + l16][w * 16 + quad * 4 + r] = v;
        }
    }
    __syncthreads();
    int n = m0 >> 12, sbase = m0 & 4095;
    #pragma unroll
    for (int p = 0; p < 8; p++) {
        int row = p * 16 + (t >> 4);
        int ch = (t & 15) * 4;
        float4 v = *(float4*)&LT[row][ch];
        *(float4*)&out[((long)n * 256 + j0 + row) * SEQ + sbase + ch] = v;
    }
}

// ---------------------------------------------------------------------------
extern "C" void kernel_launch(void* const* d_in, const int* in_sizes, int n_in,
                              void* d_out, int out_size, void* d_ws, size_t ws_size,
                              hipStream_t stream) {
    const float* x    = (const float*)d_in[0];
    const float* ln1w = (const float*)d_in[1];
    const float* ln1b = (const float*)d_in[2];
    const float* WQ   = (const float*)d_in[3];
    const float* WK   = (const float*)d_in[4];
    const float* WV   = (const float*)d_in[5];
    const float* ln2w = (const float*)d_in[6];
    const float* ln2b = (const float*)d_in[7];
    const float* W1   = (const float*)d_in[8];
    const float* b1   = (const float*)d_in[9];
    const float* W2   = (const float*)d_in[10];
    const float* b2   = (const float*)d_in[11];
    float* out = (float*)d_out;

    char* p = (char*)d_ws;
    u16* norm   = (u16*)p;   p += (size_t)8192 * 256 * 2;
    u16* BtQKV  = (u16*)p;   p += (size_t)768 * 256 * 2;
    u16* W1t    = (u16*)p;   p += (size_t)256 * 256 * 2;
    u16* W2t    = (u16*)p;   p += (size_t)256 * 256 * 2;
    u16* Qb     = (u16*)p;   p += (size_t)NHT * SEQ * 64 * 2;
    u16* Kb     = (u16*)p;   p += (size_t)NHT * SEQ * 64 * 2;
    u16* Vb     = (u16*)p;   p += (size_t)NHT * SEQ * 64 * 2;
    float* D4   = (float*)p; p += (size_t)4 * NHT * SEQ * 4;
    u16* Vt     = (u16*)p;   p += (size_t)NHT * SEQ * 64 * 2;
    float* acat2= (float*)p; p += (size_t)2 * 8192 * 256 * 4;
    float* acat = (float*)p; p += (size_t)8192 * 256 * 4;
    u16* h2     = (u16*)p;   p += (size_t)8192 * 256 * 2;
    u16* tbuf   = (u16*)p;   p += (size_t)8192 * 256 * 2;

    k_pack<<<1280, 256, 0, stream>>>(WQ, WK, WV, W1, W2, BtQKV, W1t, W2t);
    k_ln1<<<dim3(128, 2), 256, 0, stream>>>(x, ln1w, ln1b, norm);
    k_qkv<<<dim3(128, 6), 256, 0, stream>>>(norm, BtQKV, Qb, Kb, Vb);
    k_pass1<<<dim3(32, 8, 4), 256, 0, stream>>>(Qb, Kb, D4);
    k_scaleV<<<dim3(64, 8), 256, 0, stream>>>(Vb, D4, Vt);
    k_pass2<<<dim3(64, 8, 2), 256, 0, stream>>>(Qb, Kb, Vt, acat2);
    k_ln2<<<dim3(128, 2), 256, 0, stream>>>(x, acat2, ln2w, ln2b, h2, acat);
    k_mlp1<<<dim3(128, 2), 256, 0, stream>>>(h2, W1t, b1, tbuf);
    k_mlp2<<<dim3(128, 2), 256, 0, stream>>>(tbuf, W2t, b2, acat, out);
}

// Round 8
// 272.496 us; speedup vs baseline: 1.6590x; 1.0572x over previous
//
#include <hip/hip_runtime.h>
#include <math.h>

#define SEQ 4096
#define CH  256
#define NHT 8      // N * HEADS
#define DHD 64

// Q is pre-scaled by log2(e)/64 at projection time, so both attention passes
// compute exp2(S) with zero multiplies.
#define QSCALE 0.0225421092f

using bf16x8 = __attribute__((ext_vector_type(8))) short;
using f32x4  = __attribute__((ext_vector_type(4))) float;
typedef unsigned short u16;
typedef unsigned int   u32;

__device__ __forceinline__ u16 f2bf(float f) {
    u32 u = __float_as_uint(f);
    u = (u + 0x7fffu + ((u >> 16) & 1u)) >> 16;
    return (u16)u;
}
__device__ __forceinline__ float bf2f(u16 h) {
    return __uint_as_float(((u32)h) << 16);
}

// ---------------------------------------------------------------------------
// Prep: weight pack (blocks 0..1279) + LN1 (blocks 1280..1535), one launch.
// ---------------------------------------------------------------------------
__global__ __launch_bounds__(256) void k_prep(const float* __restrict__ x,
                                              const float* __restrict__ ln1w,
                                              const float* __restrict__ ln1b,
                                              const float* __restrict__ WQ,
                                              const float* __restrict__ WK,
                                              const float* __restrict__ WV,
                                              const float* __restrict__ W1,
                                              const float* __restrict__ W2,
                                              u16* __restrict__ norm,
                                              u16* __restrict__ BtQKV,
                                              u16* __restrict__ W1t,
                                              u16* __restrict__ W2t)
{
    __shared__ float tile[32][257];
    __shared__ float mu[32], rs[32];
    int bid = blockIdx.x;
    int t = threadIdx.x;
    if (bid < 1280) {   // ---- pack ----
        int id = bid * 256 + t;
        if (id < 768 * 256) {
            int j = id >> 8, c = id & 255;
            int which = j >> 8, h = (j >> 6) & 3, d = j & 63;
            const float* W = (which == 0) ? WQ : (which == 1) ? WK : WV;
            BtQKV[id] = f2bf(W[(h * 256 + c) * 64 + d]);
        } else if (id < 768 * 256 + 65536) {
            int jj = id - 768 * 256;
            int j = jj >> 8, c = jj & 255;
            W1t[jj] = f2bf(W1[c * 256 + j]);
        } else if (id < 768 * 256 + 2 * 65536) {
            int jj = id - 768 * 256 - 65536;
            int j = jj >> 8, c = jj & 255;
            W2t[jj] = f2bf(W2[c * 256 + j]);
        }
        return;
    }
    // ---- LN1 (R2-proven body) ----
    int b2i = bid - 1280;
    int n = b2i >> 7, s0 = (b2i & 127) * 32;
    int sl = t & 31, cg = t >> 5;
    for (int cc = 0; cc < 256; cc += 8) {
        int c = cc + cg;
        tile[sl][c] = x[(n * 256 + c) * SEQ + s0 + sl];
    }
    __syncthreads();
    int wv = t >> 6, l = t & 63;
    for (int rr = 0; rr < 8; rr++) {
        int s = wv * 8 + rr;
        float a0 = tile[s][l], a1 = tile[s][l + 64], a2 = tile[s][l + 128], a3 = tile[s][l + 192];
        float sm = a0 + a1 + a2 + a3;
        float sq = a0 * a0 + a1 * a1 + a2 * a2 + a3 * a3;
        for (int off = 32; off; off >>= 1) { sm += __shfl_xor(sm, off); sq += __shfl_xor(sq, off); }
        if (l == 0) {
            float m = sm * (1.f / 256.f);
            mu[s] = m;
            rs[s] = rsqrtf(sq * (1.f / 256.f) - m * m + 1e-5f);
        }
    }
    __syncthreads();
    float ww = ln1w[t], bb = ln1b[t];
    for (int s = 0; s < 32; s++) {
        float v = (tile[s][t] - mu[s]) * rs[s] * ww + bb;
        norm[(n * SEQ + s0 + s) * 256 + t] = f2bf(v);
    }
}

// ---------------------------------------------------------------------------
// QKV projection, barrier-free (R4-proven). Q outputs pre-scaled by QSCALE.
// ---------------------------------------------------------------------------
__global__ __launch_bounds__(256) void k_qkv(const u16* __restrict__ norm,
                                             const u16* __restrict__ Bt,
                                             u16* __restrict__ Qo,
                                             u16* __restrict__ Ko,
                                             u16* __restrict__ Vo)
{
    int m0 = blockIdx.x * 64, j0 = blockIdx.y * 128;
    int t = threadIdx.x, w = t >> 6, lane = t & 63, quad = lane >> 4, l16 = lane & 15;
    const u16* Ap = norm + (long)(m0 + w * 16 + l16) * 256;
    const u16* Bp = Bt + (long)j0 * 256;
    f32x4 z = {0.f, 0.f, 0.f, 0.f};
    f32x4 acc[8];
    #pragma unroll
    for (int j = 0; j < 8; j++) acc[j] = z;
    #pragma unroll
    for (int kc = 0; kc < 8; kc++) {
        bf16x8 a = *(const bf16x8*)&Ap[kc * 32 + quad * 8];
        #pragma unroll
        for (int j = 0; j < 8; j++) {
            bf16x8 b = *(const bf16x8*)&Bp[(long)(j * 16 + l16) * 256 + kc * 32 + quad * 8];
            acc[j] = __builtin_amdgcn_mfma_f32_16x16x32_bf16(a, b, acc[j], 0, 0, 0);
        }
    }
    #pragma unroll
    for (int j = 0; j < 8; j++) {
        int col = j0 + j * 16 + l16;
        int which = col >> 8, h = (col >> 6) & 3, d = col & 63;
        u16* dst = (which == 0) ? Qo : (which == 1) ? Ko : Vo;
        float sc = (which == 0) ? QSCALE : 1.0f;
        #pragma unroll
        for (int r = 0; r < 4; r++) {
            int m = m0 + w * 16 + quad * 4 + r;
            int n = m >> 12, s = m & 4095;
            dst[((n * 4 + h) * SEQ + s) * 64 + d] = f2bf(acc[j][r] * sc);
        }
    }
}

// ---------------------------------------------------------------------------
// Pass 1, WAVE-SPLIT-Q (R6 pass2 recipe): zero loop barriers. Each wave holds
// all 128 k-rows in regs (Kf[8][2]) and iterates its PRIVATE 256-q range with
// prefetched Q B-frags (16 MFMA : 2 global loads per step). Tail: shfl reduce
// over 16 q-lanes + LDS-atomic cross-wave sum (2 barriers total).
// Grid (32 k-tiles, 8 nh, 4 q-chunks).
// ---------------------------------------------------------------------------
__global__ __launch_bounds__(256) void k_pass1(const u16* __restrict__ Q,
                                               const u16* __restrict__ Km,
                                               float* __restrict__ D4)
{
    __shared__ float Dred[128];
    int nh = blockIdx.y, k0 = blockIdx.x * 128, qc = blockIdx.z;
    const u16* Qh = Q + (long)nh * SEQ * 64;
    const u16* Kh = Km + (long)nh * SEQ * 64;
    int t = threadIdx.x, w = t >> 6, lane = t & 63, quad = lane >> 4, l16 = lane & 15;
    bf16x8 Kf[8][2];
    #pragma unroll
    for (int i = 0; i < 8; i++) {
        Kf[i][0] = *(const bf16x8*)&Kh[(k0 + i * 16 + l16) * 64 + quad * 8];
        Kf[i][1] = *(const bf16x8*)&Kh[(k0 + i * 16 + l16) * 64 + 32 + quad * 8];
    }
    if (t < 128) Dred[t] = 0.f;
    f32x4 z = {0.f, 0.f, 0.f, 0.f};
    float Dacc[8][4] = {};
    const int qw0 = qc * 1024 + w * 256;
    bf16x8 b0 = *(const bf16x8*)&Qh[(qw0 + l16) * 64 + quad * 8];
    bf16x8 b1 = *(const bf16x8*)&Qh[(qw0 + l16) * 64 + 32 + quad * 8];
    for (int step = 0; step < 16; step++) {
        int q = qw0 + step * 16;
        bf16x8 n0, n1;
        if (step < 15) {
            n0 = *(const bf16x8*)&Qh[(q + 16 + l16) * 64 + quad * 8];
            n1 = *(const bf16x8*)&Qh[(q + 16 + l16) * 64 + 32 + quad * 8];
        }
        #pragma unroll
        for (int i = 0; i < 8; i++) {
            f32x4 acc = z;
            acc = __builtin_amdgcn_mfma_f32_16x16x32_bf16(Kf[i][0], b0, acc, 0, 0, 0);
            acc = __builtin_amdgcn_mfma_f32_16x16x32_bf16(Kf[i][1], b1, acc, 0, 0, 0);
            #pragma unroll
            for (int r = 0; r < 4; r++) Dacc[i][r] += exp2f(acc[r]);
        }
        b0 = n0; b1 = n1;
    }
    #pragma unroll
    for (int i = 0; i < 8; i++)
        #pragma unroll
        for (int r = 0; r < 4; r++) {
            float v = Dacc[i][r];
            v += __shfl_xor(v, 1); v += __shfl_xor(v, 2);
            v += __shfl_xor(v, 4); v += __shfl_xor(v, 8);
            Dacc[i][r] = v;
        }
    __syncthreads();
    if (l16 == 0) {
        #pragma unroll
        for (int i = 0; i < 8; i++)
            #pragma unroll
            for (int r = 0; r < 4; r++)
                atomicAdd(&Dred[i * 16 + quad * 4 + r], Dacc[i][r]);
    }
    __syncthreads();
    if (t < 128) D4[((long)(qc * NHT + nh)) * SEQ + k0 + t] = Dred[t];
}

// ---------------------------------------------------------------------------
// Scale+transpose V (R2-proven): Vt[nh][d][k] = V[nh][k][d] / D[nh][k].
// ---------------------------------------------------------------------------
__global__ __launch_bounds__(256) void k_scaleV(const u16* __restrict__ V,
                                                const float* __restrict__ D4,
                                                u16* __restrict__ Vt)
{
    __shared__ float tile[64][65];
    int nh = blockIdx.y, k0 = blockIdx.x * 64;
    int t = threadIdx.x;
    int d = t & 63, kk = t >> 6;
    const u16* Vh = V + (long)nh * SEQ * 64;
    for (int p = 0; p < 16; p++) {
        int k = p * 4 + kk;
        float Dv = D4[((long)(0 * NHT + nh)) * SEQ + k0 + k]
                 + D4[((long)(1 * NHT + nh)) * SEQ + k0 + k]
                 + D4[((long)(2 * NHT + nh)) * SEQ + k0 + k]
                 + D4[((long)(3 * NHT + nh)) * SEQ + k0 + k];
        tile[k][d] = bf2f(Vh[(k0 + k) * 64 + d]) * (1.f / Dv);
    }
    __syncthreads();
    int k2 = t & 63, d4 = t >> 6;
    u16* Vth = Vt + (long)nh * 64 * SEQ;
    for (int p = 0; p < 16; p++) {
        int dd = p * 4 + d4;
        Vth[dd * SEQ + k0 + k2] = f2bf(tile[k2][dd]);
    }
}

// ---------------------------------------------------------------------------
// Pass 2 (R7-proven) — R8 delta: truncating bf16 pack (perm on raw exp bits,
// no rounding adds). Grid (64 q-tiles, 8 nh, 2 k-chunks).
// ---------------------------------------------------------------------------
__global__ __launch_bounds__(256) void k_pass2(const u16* __restrict__ Q,
                                               const u16* __restrict__ Km,
                                               const u16* __restrict__ Vt,
                                               float* __restrict__ acat2)
{
    __shared__ __align__(16) unsigned char smem[34816];
    u16 (*lP)[64][36] = (u16(*)[64][36])smem;               // 4 strips, 18432 B
    float (*SA)[68] = (float(*)[68])smem;                   // 17408 B
    float (*SB)[68] = (float(*)[68])(smem + 17408);         // 17408 B

    int nh = blockIdx.y, q0 = blockIdx.x * 64, kcid = blockIdx.z;
    int n = nh >> 2, h = nh & 3;
    const u16* Qh = Q + (long)nh * SEQ * 64;
    const u16* Kh = Km + (long)nh * SEQ * 64;
    const u16* Vh = Vt + (long)nh * 64 * SEQ;
    int t = threadIdx.x, w = t >> 6, lane = t & 63, quad = lane >> 4, l16 = lane & 15;
    bf16x8 Qf[4][2];
    #pragma unroll
    for (int jq = 0; jq < 4; jq++)
        #pragma unroll
        for (int ch = 0; ch < 2; ch++)
            Qf[jq][ch] = *(const bf16x8*)&Qh[(q0 + jq * 16 + l16) * 64 + ch * 32 + quad * 8];
    f32x4 z = {0.f, 0.f, 0.f, 0.f};
    f32x4 accO[4][4];
    #pragma unroll
    for (int jq = 0; jq < 4; jq++)
        #pragma unroll
        for (int jd = 0; jd < 4; jd++) accO[jq][jd] = z;

    const int kw0 = kcid * 2048 + w * 512;
    bf16x8 kA[2][2], nA[2][2];
    #pragma unroll
    for (int ksub = 0; ksub < 2; ksub++) {
        kA[ksub][0] = *(const bf16x8*)&Kh[(kw0 + ksub * 16 + l16) * 64 + quad * 8];
        kA[ksub][1] = *(const bf16x8*)&Kh[(kw0 + ksub * 16 + l16) * 64 + 32 + quad * 8];
    }
    for (int step = 0; step < 16; step++) {
        int k0 = kw0 + step * 32;
        if (step < 15) {
            #pragma unroll
            for (int ksub = 0; ksub < 2; ksub++) {
                nA[ksub][0] = *(const bf16x8*)&Kh[(k0 + 32 + ksub * 16 + l16) * 64 + quad * 8];
                nA[ksub][1] = *(const bf16x8*)&Kh[(k0 + 32 + ksub * 16 + l16) * 64 + 32 + quad * 8];
            }
        }
        #pragma unroll
        for (int ksub = 0; ksub < 2; ksub++) {
            #pragma unroll
            for (int jq = 0; jq < 4; jq++) {
                f32x4 acc = z;
                acc = __builtin_amdgcn_mfma_f32_16x16x32_bf16(kA[ksub][0], Qf[jq][0], acc, 0, 0, 0);
                acc = __builtin_amdgcn_mfma_f32_16x16x32_bf16(kA[ksub][1], Qf[jq][1], acc, 0, 0, 0);
                u32 e0 = __float_as_uint(exp2f(acc[0]));
                u32 e1 = __float_as_uint(exp2f(acc[1]));
                u32 e2 = __float_as_uint(exp2f(acc[2]));
                u32 e3 = __float_as_uint(exp2f(acc[3]));
                uint2 pk;
                pk.x = __builtin_amdgcn_perm(e1, e0, 0x07060302u);
                pk.y = __builtin_amdgcn_perm(e3, e2, 0x07060302u);
                *(uint2*)&lP[w][jq * 16 + l16][ksub * 16 + quad * 4] = pk;
            }
        }
        #pragma unroll
        for (int jq = 0; jq < 4; jq++) {
            bf16x8 pa = *(const bf16x8*)&lP[w][jq * 16 + l16][quad * 8];
            #pragma unroll
            for (int jd = 0; jd < 4; jd++) {
                bf16x8 vb = *(const bf16x8*)&Vh[(jd * 16 + l16) * SEQ + k0 + quad * 8];
                accO[jq][jd] = __builtin_amdgcn_mfma_f32_16x16x32_bf16(pa, vb, accO[jq][jd], 0, 0, 0);
            }
        }
        #pragma unroll
        for (int ksub = 0; ksub < 2; ksub++) {
            kA[ksub][0] = nA[ksub][0];
            kA[ksub][1] = nA[ksub][1];
        }
    }
    __syncthreads();
    if (w >= 2) {
        float (*S)[68] = (w == 2) ? SA : SB;
        #pragma unroll
        for (int jq = 0; jq < 4; jq++)
            #pragma unroll
            for (int jd = 0; jd < 4; jd++)
                #pragma unroll
                for (int r = 0; r < 4; r++)
                    S[jq * 16 + quad * 4 + r][jd * 16 + l16] = accO[jq][jd][r];
    }
    __syncthreads();
    if (w < 2) {
        float (*S)[68] = (w == 0) ? SA : SB;
        #pragma unroll
        for (int jq = 0; jq < 4; jq++)
            #pragma unroll
            for (int jd = 0; jd < 4; jd++)
                #pragma unroll
                for (int r = 0; r < 4; r++) {
                    float v = accO[jq][jd][r] + S[jq * 16 + quad * 4 + r][jd * 16 + l16];
                    S[jq * 16 + quad * 4 + r][jd * 16 + l16] = v;
                }
    }
    __syncthreads();
    float* dst = acat2 + (long)kcid * 8192 * 256;
    #pragma unroll
    for (int p = 0; p < 4; p++) {
        int row = p * 16 + (t >> 4);
        int ch = (t & 15) * 4;
        float4 va = *(float4*)&SA[row][ch];
        float4 vb = *(float4*)&SB[row][ch];
        float4 o = make_float4(va.x + vb.x, va.y + vb.y, va.z + vb.z, va.w + vb.w);
        *(float4*)&dst[((long)n * SEQ + q0 + row) * 256 + h * 64 + ch] = o;
    }
}

// ---------------------------------------------------------------------------
// LN2 + partial-sum fold (R6-proven).
// ---------------------------------------------------------------------------
__global__ __launch_bounds__(256) void k_ln2(const float* __restrict__ x,
                                             const float* __restrict__ acat2,
                                             const float* __restrict__ w,
                                             const float* __restrict__ b,
                                             u16* __restrict__ h2,
                                             float* __restrict__ acat)
{
    __shared__ float tile[32][257];
    __shared__ float mu[32], rs[32];
    int n = blockIdx.y, s0 = blockIdx.x * 32;
    int t = threadIdx.x;
    int sl = t & 31, cg = t >> 5;
    for (int cc = 0; cc < 256; cc += 8) {
        int c = cc + cg;
        tile[sl][c] = x[(n * 256 + c) * SEQ + s0 + sl];
    }
    __syncthreads();
    const long STRIDE = (long)8192 * 256;
    for (int s = 0; s < 32; s++) {
        long idx = ((long)n * SEQ + s0 + s) * 256 + t;
        float a = acat2[idx] + acat2[idx + STRIDE];
        acat[idx] = a;
        tile[s][t] += a;
    }
    __syncthreads();
    int wv = t >> 6, l = t & 63;
    for (int rr = 0; rr < 8; rr++) {
        int s = wv * 8 + rr;
        float a0 = tile[s][l], a1 = tile[s][l + 64], a2 = tile[s][l + 128], a3 = tile[s][l + 192];
        float sm = a0 + a1 + a2 + a3;
        float sq = a0 * a0 + a1 * a1 + a2 * a2 + a3 * a3;
        for (int off = 32; off; off >>= 1) { sm += __shfl_xor(sm, off); sq += __shfl_xor(sq, off); }
        if (l == 0) {
            float m = sm * (1.f / 256.f);
            mu[s] = m;
            rs[s] = rsqrtf(sq * (1.f / 256.f) - m * m + 1e-5f);
        }
    }
    __syncthreads();
    float ww = w[t], bb = b[t];
    for (int s = 0; s < 32; s++) {
        float v = (tile[s][t] - mu[s]) * rs[s] * ww + bb;
        h2[((long)n * SEQ + s0 + s) * 256 + t] = f2bf(v);
    }
}

// ---------------------------------------------------------------------------
// Fused MLP: out = gelu(h2@W1+b1)@W2 + b2 + acat, transposed to [N][C][S].
// m-tile 32, grid 256. GEMM1 computed as T^T (A=W1t j-rows, B=h2 m-rows) so
// each lane holds 4 consecutive j per m -> packed uint2 write into lT[m][j]
// (GEMM2 A-layout, pass2's lP trick). GEMM2: A from lT, B=W2t c-rows from
// global. Epilogue: bias + residual -> LT[c][m] -> coalesced transpose store.
// ---------------------------------------------------------------------------
__global__ __launch_bounds__(256) void k_mlp(const u16* __restrict__ h2,
                                             const u16* __restrict__ W1t,
                                             const float* __restrict__ b1v,
                                             const u16* __restrict__ W2t,
                                             const float* __restrict__ b2v,
                                             const float* __restrict__ acat,
                                             float* __restrict__ out)
{
    __shared__ __align__(16) unsigned char smem[36864];
    u16 (*lT)[264] = (u16(*)[264])smem;     // [32][264] = 16896 B
    float (*LT)[36] = (float(*)[36])smem;   // [256][36] = 36864 B

    int m0 = blockIdx.x * 32;
    int t = threadIdx.x, w = t >> 6, lane = t & 63, quad = lane >> 4, l16 = lane & 15;
    f32x4 z = {0.f, 0.f, 0.f, 0.f};

    // GEMM1: T^T[j][m], wave w owns j-range [w*64, +64)
    f32x4 acc[4][2];
    #pragma unroll
    for (int js = 0; js < 4; js++)
        #pragma unroll
        for (int ms = 0; ms < 2; ms++) acc[js][ms] = z;
    #pragma unroll
    for (int kc = 0; kc < 8; kc++) {
        bf16x8 a[4], b[2];
        #pragma unroll
        for (int js = 0; js < 4; js++)
            a[js] = *(const bf16x8*)&W1t[(long)(w * 64 + js * 16 + l16) * 256 + kc * 32 + quad * 8];
        #pragma unroll
        for (int ms = 0; ms < 2; ms++)
            b[ms] = *(const bf16x8*)&h2[(long)(m0 + ms * 16 + l16) * 256 + kc * 32 + quad * 8];
        #pragma unroll
        for (int js = 0; js < 4; js++)
            #pragma unroll
            for (int ms = 0; ms < 2; ms++)
                acc[js][ms] = __builtin_amdgcn_mfma_f32_16x16x32_bf16(a[js], b[ms], acc[js][ms], 0, 0, 0);
    }
    // gelu + bias, pack 4 consecutive j per (js,ms) into lT[m][j]
    #pragma unroll
    for (int js = 0; js < 4; js++) {
        #pragma unroll
        for (int ms = 0; ms < 2; ms++) {
            u32 e[4];
            #pragma unroll
            for (int r = 0; r < 4; r++) {
                int j = w * 64 + js * 16 + quad * 4 + r;
                float v = acc[js][ms][r] + b1v[j];
                float g = 0.5f * v * (1.f + erff(v * 0.70710678118f));
                u32 u = __float_as_uint(g);
                e[r] = u + 0x7fffu + ((u >> 16) & 1u);
            }
            uint2 pk;
            pk.x = __builtin_amdgcn_perm(e[1], e[0], 0x07060302u);
            pk.y = __builtin_amdgcn_perm(e[3], e[2], 0x07060302u);
            *(uint2*)&lT[ms * 16 + l16][w * 64 + js * 16 + quad * 4] = pk;
        }
    }
    __syncthreads();
    // GEMM2: wave w owns c-range [w*64, +64), all 32 m
    f32x4 acc2[2][4];
    #pragma unroll
    for (int ms = 0; ms < 2; ms++)
        #pragma unroll
        for (int cs = 0; cs < 4; cs++) acc2[ms][cs] = z;
    #pragma unroll
    for (int kc = 0; kc < 8; kc++) {
        bf16x8 pa[2], wb[4];
        #pragma unroll
        for (int ms = 0; ms < 2; ms++)
            pa[ms] = *(const bf16x8*)&lT[ms * 16 + l16][kc * 32 + quad * 8];
        #pragma unroll
        for (int cs = 0; cs < 4; cs++)
            wb[cs] = *(const bf16x8*)&W2t[(long)(w * 64 + cs * 16 + l16) * 256 + kc * 32 + quad * 8];
        #pragma unroll
        for (int ms = 0; ms < 2; ms++)
            #pragma unroll
            for (int cs = 0; cs < 4; cs++)
                acc2[ms][cs] = __builtin_amdgcn_mfma_f32_16x16x32_bf16(pa[ms], wb[cs], acc2[ms][cs], 0, 0, 0);
    }
    __syncthreads();   // lT reads done before LT overlay
    // epilogue: + b2 + residual, write LT[c][m]
    #pragma unroll
    for (int ms = 0; ms < 2; ms++)
        #pragma unroll
        for (int cs = 0; cs < 4; cs++) {
            int c = w * 64 + cs * 16 + l16;
            float bj = b2v[c];
            float4 fv;
            float vv[4];
            #pragma unroll
            for (int r = 0; r < 4; r++) {
                int m = m0 + ms * 16 + quad * 4 + r;
                vv[r] = acc2[ms][cs][r] + bj + acat[(long)m * 256 + c];
            }
            fv = make_float4(vv[0], vv[1], vv[2], vv[3]);
            *(float4*)&LT[c][ms * 16 + quad * 4] = fv;
        }
    __syncthreads();
    int n = m0 >> 12, sbase = m0 & 4095;
    #pragma unroll
    for (int p = 0; p < 8; p++) {
        int row = p * 32 + (t >> 3);
        int ch = (t & 7) * 4;
        float4 v = *(float4*)&LT[row][ch];
        *(float4*)&out[((long)n * 256 + row) * SEQ + sbase + ch] = v;
    }
}

// ---------------------------------------------------------------------------
extern "C" void kernel_launch(void* const* d_in, const int* in_sizes, int n_in,
                              void* d_out, int out_size, void* d_ws, size_t ws_size,
                              hipStream_t stream) {
    const float* x    = (const float*)d_in[0];
    const float* ln1w = (const float*)d_in[1];
    const float* ln1b = (const float*)d_in[2];
    const float* WQ   = (const float*)d_in[3];
    const float* WK   = (const float*)d_in[4];
    const float* WV   = (const float*)d_in[5];
    const float* ln2w = (const float*)d_in[6];
    const float* ln2b = (const float*)d_in[7];
    const float* W1   = (const float*)d_in[8];
    const float* b1   = (const float*)d_in[9];
    const float* W2   = (const float*)d_in[10];
    const float* b2   = (const float*)d_in[11];
    float* out = (float*)d_out;

    char* p = (char*)d_ws;
    u16* norm   = (u16*)p;   p += (size_t)8192 * 256 * 2;
    u16* BtQKV  = (u16*)p;   p += (size_t)768 * 256 * 2;
    u16* W1t    = (u16*)p;   p += (size_t)256 * 256 * 2;
    u16* W2t    = (u16*)p;   p += (size_t)256 * 256 * 2;
    u16* Qb     = (u16*)p;   p += (size_t)NHT * SEQ * 64 * 2;
    u16* Kb     = (u16*)p;   p += (size_t)NHT * SEQ * 64 * 2;
    u16* Vb     = (u16*)p;   p += (size_t)NHT * SEQ * 64 * 2;
    float* D4   = (float*)p; p += (size_t)4 * NHT * SEQ * 4;
    u16* Vt     = (u16*)p;   p += (size_t)NHT * SEQ * 64 * 2;
    float* acat2= (float*)p; p += (size_t)2 * 8192 * 256 * 4;
    float* acat = (float*)p; p += (size_t)8192 * 256 * 4;
    u16* h2     = (u16*)p;   p += (size_t)8192 * 256 * 2;

    k_prep<<<1536, 256, 0, stream>>>(x, ln1w, ln1b, WQ, WK, WV, W1, W2,
                                     norm, BtQKV, W1t, W2t);
    k_qkv<<<dim3(128, 6), 256, 0, stream>>>(norm, BtQKV, Qb, Kb, Vb);
    k_pass1<<<dim3(32, 8, 4), 256, 0, stream>>>(Qb, Kb, D4);
    k_scaleV<<<dim3(64, 8), 256, 0, stream>>>(Vb, D4, Vt);
    k_pass2<<<dim3(64, 8, 2), 256, 0, stream>>>(Qb, Kb, Vt, acat2);
    k_ln2<<<dim3(128, 2), 256, 0, stream>>>(x, acat2, ln2w, ln2b, h2, acat);
    k_mlp<<<256, 256, 0, stream>>>(h2, W1t, b1, W2t, b2, acat, out);
}

// Round 9
// 257.640 us; speedup vs baseline: 1.7547x; 1.0577x over previous
//
#include <hip/hip_runtime.h>
#include <math.h>

#define SEQ 4096
#define CH  256
#define NHT 8      // N * HEADS
#define DHD 64

// Q is pre-scaled by log2(e)/64 at projection time, so both attention passes
// compute exp2(S) with zero multiplies.
#define QSCALE 0.0225421092f

using bf16x8 = __attribute__((ext_vector_type(8))) short;
using f32x4  = __attribute__((ext_vector_type(4))) float;
typedef unsigned short u16;
typedef unsigned int   u32;

__device__ __forceinline__ u16 f2bf(float f) {
    u32 u = __float_as_uint(f);
    u = (u + 0x7fffu + ((u >> 16) & 1u)) >> 16;
    return (u16)u;
}
__device__ __forceinline__ float bf2f(u16 h) {
    return __uint_as_float(((u32)h) << 16);
}
// raw v_exp_f32 — exp2f without -ffast-math is an OCML call (~8 VALU ops)
__device__ __forceinline__ float fexp2(float x) {
    return __builtin_amdgcn_exp2f(x);
}

// ---------------------------------------------------------------------------
// Prep: weight pack (blocks 0..1279) + LN1 (blocks 1280..1535), one launch.
// ---------------------------------------------------------------------------
__global__ __launch_bounds__(256) void k_prep(const float* __restrict__ x,
                                              const float* __restrict__ ln1w,
                                              const float* __restrict__ ln1b,
                                              const float* __restrict__ WQ,
                                              const float* __restrict__ WK,
                                              const float* __restrict__ WV,
                                              const float* __restrict__ W1,
                                              const float* __restrict__ W2,
                                              u16* __restrict__ norm,
                                              u16* __restrict__ BtQKV,
                                              u16* __restrict__ W1t,
                                              u16* __restrict__ W2t)
{
    __shared__ float tile[32][257];
    __shared__ float mu[32], rs[32];
    int bid = blockIdx.x;
    int t = threadIdx.x;
    if (bid < 1280) {   // ---- pack ----
        int id = bid * 256 + t;
        if (id < 768 * 256) {
            int j = id >> 8, c = id & 255;
            int which = j >> 8, h = (j >> 6) & 3, d = j & 63;
            const float* W = (which == 0) ? WQ : (which == 1) ? WK : WV;
            BtQKV[id] = f2bf(W[(h * 256 + c) * 64 + d]);
        } else if (id < 768 * 256 + 65536) {
            int jj = id - 768 * 256;
            int j = jj >> 8, c = jj & 255;
            W1t[jj] = f2bf(W1[c * 256 + j]);
        } else if (id < 768 * 256 + 2 * 65536) {
            int jj = id - 768 * 256 - 65536;
            int j = jj >> 8, c = jj & 255;
            W2t[jj] = f2bf(W2[c * 256 + j]);
        }
        return;
    }
    // ---- LN1 ----
    int b2i = bid - 1280;
    int n = b2i >> 7, s0 = (b2i & 127) * 32;
    int sl = t & 31, cg = t >> 5;
    for (int cc = 0; cc < 256; cc += 8) {
        int c = cc + cg;
        tile[sl][c] = x[(n * 256 + c) * SEQ + s0 + sl];
    }
    __syncthreads();
    int wv = t >> 6, l = t & 63;
    for (int rr = 0; rr < 8; rr++) {
        int s = wv * 8 + rr;
        float a0 = tile[s][l], a1 = tile[s][l + 64], a2 = tile[s][l + 128], a3 = tile[s][l + 192];
        float sm = a0 + a1 + a2 + a3;
        float sq = a0 * a0 + a1 * a1 + a2 * a2 + a3 * a3;
        for (int off = 32; off; off >>= 1) { sm += __shfl_xor(sm, off); sq += __shfl_xor(sq, off); }
        if (l == 0) {
            float m = sm * (1.f / 256.f);
            mu[s] = m;
            rs[s] = rsqrtf(sq * (1.f / 256.f) - m * m + 1e-5f);
        }
    }
    __syncthreads();
    float ww = ln1w[t], bb = ln1b[t];
    for (int s = 0; s < 32; s++) {
        float v = (tile[s][t] - mu[s]) * rs[s] * ww + bb;
        norm[(n * SEQ + s0 + s) * 256 + t] = f2bf(v);
    }
}

// ---------------------------------------------------------------------------
// QKV projection, barrier-free (R4-proven). Q outputs pre-scaled by QSCALE.
// ---------------------------------------------------------------------------
__global__ __launch_bounds__(256) void k_qkv(const u16* __restrict__ norm,
                                             const u16* __restrict__ Bt,
                                             u16* __restrict__ Qo,
                                             u16* __restrict__ Ko,
                                             u16* __restrict__ Vo)
{
    int m0 = blockIdx.x * 64, j0 = blockIdx.y * 128;
    int t = threadIdx.x, w = t >> 6, lane = t & 63, quad = lane >> 4, l16 = lane & 15;
    const u16* Ap = norm + (long)(m0 + w * 16 + l16) * 256;
    const u16* Bp = Bt + (long)j0 * 256;
    f32x4 z = {0.f, 0.f, 0.f, 0.f};
    f32x4 acc[8];
    #pragma unroll
    for (int j = 0; j < 8; j++) acc[j] = z;
    #pragma unroll
    for (int kc = 0; kc < 8; kc++) {
        bf16x8 a = *(const bf16x8*)&Ap[kc * 32 + quad * 8];
        #pragma unroll
        for (int j = 0; j < 8; j++) {
            bf16x8 b = *(const bf16x8*)&Bp[(long)(j * 16 + l16) * 256 + kc * 32 + quad * 8];
            acc[j] = __builtin_amdgcn_mfma_f32_16x16x32_bf16(a, b, acc[j], 0, 0, 0);
        }
    }
    #pragma unroll
    for (int j = 0; j < 8; j++) {
        int col = j0 + j * 16 + l16;
        int which = col >> 8, h = (col >> 6) & 3, d = col & 63;
        u16* dst = (which == 0) ? Qo : (which == 1) ? Ko : Vo;
        float sc = (which == 0) ? QSCALE : 1.0f;
        #pragma unroll
        for (int r = 0; r < 4; r++) {
            int m = m0 + w * 16 + quad * 4 + r;
            int n = m >> 12, s = m & 4095;
            dst[((n * 4 + h) * SEQ + s) * 64 + d] = f2bf(acc[j][r] * sc);
        }
    }
}

// ---------------------------------------------------------------------------
// Pass 1, wave-split-q (R8-proven), raw v_exp_f32. Grid (32, 8, 4).
// ---------------------------------------------------------------------------
__global__ __launch_bounds__(256) void k_pass1(const u16* __restrict__ Q,
                                               const u16* __restrict__ Km,
                                               float* __restrict__ D4)
{
    __shared__ float Dred[128];
    int nh = blockIdx.y, k0 = blockIdx.x * 128, qc = blockIdx.z;
    const u16* Qh = Q + (long)nh * SEQ * 64;
    const u16* Kh = Km + (long)nh * SEQ * 64;
    int t = threadIdx.x, w = t >> 6, lane = t & 63, quad = lane >> 4, l16 = lane & 15;
    bf16x8 Kf[8][2];
    #pragma unroll
    for (int i = 0; i < 8; i++) {
        Kf[i][0] = *(const bf16x8*)&Kh[(k0 + i * 16 + l16) * 64 + quad * 8];
        Kf[i][1] = *(const bf16x8*)&Kh[(k0 + i * 16 + l16) * 64 + 32 + quad * 8];
    }
    if (t < 128) Dred[t] = 0.f;
    f32x4 z = {0.f, 0.f, 0.f, 0.f};
    float Dacc[8][4] = {};
    const int qw0 = qc * 1024 + w * 256;
    bf16x8 b0 = *(const bf16x8*)&Qh[(qw0 + l16) * 64 + quad * 8];
    bf16x8 b1 = *(const bf16x8*)&Qh[(qw0 + l16) * 64 + 32 + quad * 8];
    for (int step = 0; step < 16; step++) {
        int q = qw0 + step * 16;
        bf16x8 n0, n1;
        if (step < 15) {
            n0 = *(const bf16x8*)&Qh[(q + 16 + l16) * 64 + quad * 8];
            n1 = *(const bf16x8*)&Qh[(q + 16 + l16) * 64 + 32 + quad * 8];
        }
        #pragma unroll
        for (int i = 0; i < 8; i++) {
            f32x4 acc = z;
            acc = __builtin_amdgcn_mfma_f32_16x16x32_bf16(Kf[i][0], b0, acc, 0, 0, 0);
            acc = __builtin_amdgcn_mfma_f32_16x16x32_bf16(Kf[i][1], b1, acc, 0, 0, 0);
            #pragma unroll
            for (int r = 0; r < 4; r++) Dacc[i][r] += fexp2(acc[r]);
        }
        b0 = n0; b1 = n1;
    }
    #pragma unroll
    for (int i = 0; i < 8; i++)
        #pragma unroll
        for (int r = 0; r < 4; r++) {
            float v = Dacc[i][r];
            v += __shfl_xor(v, 1); v += __shfl_xor(v, 2);
            v += __shfl_xor(v, 4); v += __shfl_xor(v, 8);
            Dacc[i][r] = v;
        }
    __syncthreads();
    if (l16 == 0) {
        #pragma unroll
        for (int i = 0; i < 8; i++)
            #pragma unroll
            for (int r = 0; r < 4; r++)
                atomicAdd(&Dred[i * 16 + quad * 4 + r], Dacc[i][r]);
    }
    __syncthreads();
    if (t < 128) D4[((long)(qc * NHT + nh)) * SEQ + k0 + t] = Dred[t];
}

// ---------------------------------------------------------------------------
// Scale+transpose V (R2-proven): Vt[nh][d][k] = V[nh][k][d] / D[nh][k].
// ---------------------------------------------------------------------------
__global__ __launch_bounds__(256) void k_scaleV(const u16* __restrict__ V,
                                                const float* __restrict__ D4,
                                                u16* __restrict__ Vt)
{
    __shared__ float tile[64][65];
    int nh = blockIdx.y, k0 = blockIdx.x * 64;
    int t = threadIdx.x;
    int d = t & 63, kk = t >> 6;
    const u16* Vh = V + (long)nh * SEQ * 64;
    for (int p = 0; p < 16; p++) {
        int k = p * 4 + kk;
        float Dv = D4[((long)(0 * NHT + nh)) * SEQ + k0 + k]
                 + D4[((long)(1 * NHT + nh)) * SEQ + k0 + k]
                 + D4[((long)(2 * NHT + nh)) * SEQ + k0 + k]
                 + D4[((long)(3 * NHT + nh)) * SEQ + k0 + k];
        tile[k][d] = bf2f(Vh[(k0 + k) * 64 + d]) * (1.f / Dv);
    }
    __syncthreads();
    int k2 = t & 63, d4 = t >> 6;
    u16* Vth = Vt + (long)nh * 64 * SEQ;
    for (int p = 0; p < 16; p++) {
        int dd = p * 4 + d4;
        Vth[dd * SEQ + k0 + k2] = f2bf(tile[k2][dd]);
    }
}

// ---------------------------------------------------------------------------
// Pass 2 (R7/R8-proven), raw v_exp_f32. Grid (64 q-tiles, 8 nh, 2 k-chunks).
// ---------------------------------------------------------------------------
__global__ __launch_bounds__(256) void k_pass2(const u16* __restrict__ Q,
                                               const u16* __restrict__ Km,
                                               const u16* __restrict__ Vt,
                                               float* __restrict__ acat2)
{
    __shared__ __align__(16) unsigned char smem[34816];
    u16 (*lP)[64][36] = (u16(*)[64][36])smem;               // 4 strips, 18432 B
    float (*SA)[68] = (float(*)[68])smem;                   // 17408 B
    float (*SB)[68] = (float(*)[68])(smem + 17408);         // 17408 B

    int nh = blockIdx.y, q0 = blockIdx.x * 64, kcid = blockIdx.z;
    int n = nh >> 2, h = nh & 3;
    const u16* Qh = Q + (long)nh * SEQ * 64;
    const u16* Kh = Km + (long)nh * SEQ * 64;
    const u16* Vh = Vt + (long)nh * 64 * SEQ;
    int t = threadIdx.x, w = t >> 6, lane = t & 63, quad = lane >> 4, l16 = lane & 15;
    bf16x8 Qf[4][2];
    #pragma unroll
    for (int jq = 0; jq < 4; jq++)
        #pragma unroll
        for (int ch = 0; ch < 2; ch++)
            Qf[jq][ch] = *(const bf16x8*)&Qh[(q0 + jq * 16 + l16) * 64 + ch * 32 + quad * 8];
    f32x4 z = {0.f, 0.f, 0.f, 0.f};
    f32x4 accO[4][4];
    #pragma unroll
    for (int jq = 0; jq < 4; jq++)
        #pragma unroll
        for (int jd = 0; jd < 4; jd++) accO[jq][jd] = z;

    const int kw0 = kcid * 2048 + w * 512;
    bf16x8 kA[2][2], nA[2][2];
    #pragma unroll
    for (int ksub = 0; ksub < 2; ksub++) {
        kA[ksub][0] = *(const bf16x8*)&Kh[(kw0 + ksub * 16 + l16) * 64 + quad * 8];
        kA[ksub][1] = *(const bf16x8*)&Kh[(kw0 + ksub * 16 + l16) * 64 + 32 + quad * 8];
    }
    for (int step = 0; step < 16; step++) {
        int k0 = kw0 + step * 32;
        if (step < 15) {
            #pragma unroll
            for (int ksub = 0; ksub < 2; ksub++) {
                nA[ksub][0] = *(const bf16x8*)&Kh[(k0 + 32 + ksub * 16 + l16) * 64 + quad * 8];
                nA[ksub][1] = *(const bf16x8*)&Kh[(k0 + 32 + ksub * 16 + l16) * 64 + 32 + quad * 8];
            }
        }
        #pragma unroll
        for (int ksub = 0; ksub < 2; ksub++) {
            #pragma unroll
            for (int jq = 0; jq < 4; jq++) {
                f32x4 acc = z;
                acc = __builtin_amdgcn_mfma_f32_16x16x32_bf16(kA[ksub][0], Qf[jq][0], acc, 0, 0, 0);
                acc = __builtin_amdgcn_mfma_f32_16x16x32_bf16(kA[ksub][1], Qf[jq][1], acc, 0, 0, 0);
                u32 e0 = __float_as_uint(fexp2(acc[0]));
                u32 e1 = __float_as_uint(fexp2(acc[1]));
                u32 e2 = __float_as_uint(fexp2(acc[2]));
                u32 e3 = __float_as_uint(fexp2(acc[3]));
                uint2 pk;
                pk.x = __builtin_amdgcn_perm(e1, e0, 0x07060302u);
                pk.y = __builtin_amdgcn_perm(e3, e2, 0x07060302u);
                *(uint2*)&lP[w][jq * 16 + l16][ksub * 16 + quad * 4] = pk;
            }
        }
        #pragma unroll
        for (int jq = 0; jq < 4; jq++) {
            bf16x8 pa = *(const bf16x8*)&lP[w][jq * 16 + l16][quad * 8];
            #pragma unroll
            for (int jd = 0; jd < 4; jd++) {
                bf16x8 vb = *(const bf16x8*)&Vh[(jd * 16 + l16) * SEQ + k0 + quad * 8];
                accO[jq][jd] = __builtin_amdgcn_mfma_f32_16x16x32_bf16(pa, vb, accO[jq][jd], 0, 0, 0);
            }
        }
        #pragma unroll
        for (int ksub = 0; ksub < 2; ksub++) {
            kA[ksub][0] = nA[ksub][0];
            kA[ksub][1] = nA[ksub][1];
        }
    }
    __syncthreads();
    if (w >= 2) {
        float (*S)[68] = (w == 2) ? SA : SB;
        #pragma unroll
        for (int jq = 0; jq < 4; jq++)
            #pragma unroll
            for (int jd = 0; jd < 4; jd++)
                #pragma unroll
                for (int r = 0; r < 4; r++)
                    S[jq * 16 + quad * 4 + r][jd * 16 + l16] = accO[jq][jd][r];
    }
    __syncthreads();
    if (w < 2) {
        float (*S)[68] = (w == 0) ? SA : SB;
        #pragma unroll
        for (int jq = 0; jq < 4; jq++)
            #pragma unroll
            for (int jd = 0; jd < 4; jd++)
                #pragma unroll
                for (int r = 0; r < 4; r++) {
                    float v = accO[jq][jd][r] + S[jq * 16 + quad * 4 + r][jd * 16 + l16];
                    S[jq * 16 + quad * 4 + r][jd * 16 + l16] = v;
                }
    }
    __syncthreads();
    float* dst = acat2 + (long)kcid * 8192 * 256;
    #pragma unroll
    for (int p = 0; p < 4; p++) {
        int row = p * 16 + (t >> 4);
        int ch = (t & 15) * 4;
        float4 va = *(float4*)&SA[row][ch];
        float4 vb = *(float4*)&SB[row][ch];
        float4 o = make_float4(va.x + vb.x, va.y + vb.y, va.z + vb.z, va.w + vb.w);
        *(float4*)&dst[((long)n * SEQ + q0 + row) * 256 + h * 64 + ch] = o;
    }
}

// ---------------------------------------------------------------------------
// Fused tail: LN2 + MLP + residual + transposed store.  m-tile 16, grid 512.
// Phase A: tile = x^T + (acat2 fold); LN stats; h2 -> lH (bf16, LDS only).
// GEMM1 (A=W1t, B=lH) -> gelu -> packed lT (overlays tile).  GEMM2 (A=lT,
// B=W2t).  Epilogue: +b2 + residual (acat2 re-read, L2-hot) -> float4 store
// to out[n][c][s] (4 consecutive s per thread; L2 merges lines).
// ---------------------------------------------------------------------------
__global__ __launch_bounds__(256) void k_tail(const float* __restrict__ x,
                                              const float* __restrict__ acat2,
                                              const float* __restrict__ lnw,
                                              const float* __restrict__ lnb,
                                              const u16* __restrict__ W1t,
                                              const float* __restrict__ b1v,
                                              const u16* __restrict__ W2t,
                                              const float* __restrict__ b2v,
                                              float* __restrict__ out)
{
    __shared__ __align__(16) unsigned char smem[16448];  // tile fp32 / lT u16
    float (*tile)[257] = (float(*)[257])smem;            // [16][257]
    u16 (*lT)[264] = (u16(*)[264])smem;                  // [16][264] overlay
    __shared__ float mu[16], rs[16];
    __shared__ __align__(16) u16 lH[16][264];

    const long STRIDE = (long)8192 * 256;
    int m0 = blockIdx.x * 16;
    int n = m0 >> 12, s0 = m0 & 4095;
    int t = threadIdx.x, w = t >> 6, lane = t & 63, quad = lane >> 4, l16 = lane & 15;

    // ---- Phase A: x^T tile + acat fold ----
    {
        int sl = t & 15, cg = t >> 4;
        for (int cc = 0; cc < 256; cc += 16) {
            int c = cc + cg;
            tile[sl][c] = x[(n * 256 + c) * SEQ + s0 + sl];
        }
    }
    __syncthreads();
    for (int s = 0; s < 16; s++) {
        long idx = (long)(m0 + s) * 256 + t;
        tile[s][t] += acat2[idx] + acat2[idx + STRIDE];
    }
    __syncthreads();
    {
        int l = t & 63;
        for (int rr = 0; rr < 4; rr++) {
            int s = w * 4 + rr;
            float a0 = tile[s][l], a1 = tile[s][l + 64], a2 = tile[s][l + 128], a3 = tile[s][l + 192];
            float sm = a0 + a1 + a2 + a3;
            float sq = a0 * a0 + a1 * a1 + a2 * a2 + a3 * a3;
            for (int off = 32; off; off >>= 1) { sm += __shfl_xor(sm, off); sq += __shfl_xor(sq, off); }
            if (l == 0) {
                float m = sm * (1.f / 256.f);
                mu[s] = m;
                rs[s] = rsqrtf(sq * (1.f / 256.f) - m * m + 1e-5f);
            }
        }
    }
    __syncthreads();
    {
        float ww = lnw[t], bb = lnb[t];
        for (int s = 0; s < 16; s++)
            lH[s][t] = f2bf((tile[s][t] - mu[s]) * rs[s] * ww + bb);
    }
    __syncthreads();   // tile dead; lT may overlay

    f32x4 z = {0.f, 0.f, 0.f, 0.f};
    // ---- GEMM1: T^T[j][m], wave w owns j in [w*64, +64), 16 m rows ----
    f32x4 acc1[4];
    #pragma unroll
    for (int js = 0; js < 4; js++) acc1[js] = z;
    #pragma unroll
    for (int kc = 0; kc < 8; kc++) {
        bf16x8 b = *(const bf16x8*)&lH[l16][kc * 32 + quad * 8];
        #pragma unroll
        for (int js = 0; js < 4; js++) {
            bf16x8 a = *(const bf16x8*)&W1t[(long)(w * 64 + js * 16 + l16) * 256 + kc * 32 + quad * 8];
            acc1[js] = __builtin_amdgcn_mfma_f32_16x16x32_bf16(a, b, acc1[js], 0, 0, 0);
        }
    }
    #pragma unroll
    for (int js = 0; js < 4; js++) {
        u32 e[4];
        #pragma unroll
        for (int r = 0; r < 4; r++) {
            int j = w * 64 + js * 16 + quad * 4 + r;
            float v = acc1[js][r] + b1v[j];
            float g = 0.5f * v * (1.f + erff(v * 0.70710678118f));
            u32 u = __float_as_uint(g);
            e[r] = u + 0x7fffu + ((u >> 16) & 1u);
        }
        uint2 pk;
        pk.x = __builtin_amdgcn_perm(e[1], e[0], 0x07060302u);
        pk.y = __builtin_amdgcn_perm(e[3], e[2], 0x07060302u);
        *(uint2*)&lT[l16][w * 64 + js * 16 + quad * 4] = pk;
    }
    __syncthreads();
    // ---- GEMM2: wave w owns c in [w*64, +64), 16 m rows ----
    f32x4 acc2[4];
    #pragma unroll
    for (int cs = 0; cs < 4; cs++) acc2[cs] = z;
    #pragma unroll
    for (int kc = 0; kc < 8; kc++) {
        bf16x8 pa = *(const bf16x8*)&lT[l16][kc * 32 + quad * 8];
        #pragma unroll
        for (int cs = 0; cs < 4; cs++) {
            bf16x8 wb = *(const bf16x8*)&W2t[(long)(w * 64 + cs * 16 + l16) * 256 + kc * 32 + quad * 8];
            acc2[cs] = __builtin_amdgcn_mfma_f32_16x16x32_bf16(pa, wb, acc2[cs], 0, 0, 0);
        }
    }
    // ---- epilogue: + b2 + residual, direct transposed store ----
    #pragma unroll
    for (int cs = 0; cs < 4; cs++) {
        int c = w * 64 + cs * 16 + l16;
        float bj = b2v[c];
        float vv[4];
        #pragma unroll
        for (int r = 0; r < 4; r++) {
            long idx = (long)(m0 + quad * 4 + r) * 256 + c;
            vv[r] = acc2[cs][r] + bj + acat2[idx] + acat2[idx + STRIDE];
        }
        float4 o = make_float4(vv[0], vv[1], vv[2], vv[3]);
        *(float4*)&out[((long)n * 256 + c) * SEQ + s0 + quad * 4] = o;
    }
}

// ---------------------------------------------------------------------------
extern "C" void kernel_launch(void* const* d_in, const int* in_sizes, int n_in,
                              void* d_out, int out_size, void* d_ws, size_t ws_size,
                              hipStream_t stream) {
    const float* x    = (const float*)d_in[0];
    const float* ln1w = (const float*)d_in[1];
    const float* ln1b = (const float*)d_in[2];
    const float* WQ   = (const float*)d_in[3];
    const float* WK   = (const float*)d_in[4];
    const float* WV   = (const float*)d_in[5];
    const float* ln2w = (const float*)d_in[6];
    const float* ln2b = (const float*)d_in[7];
    const float* W1   = (const float*)d_in[8];
    const float* b1   = (const float*)d_in[9];
    const float* W2   = (const float*)d_in[10];
    const float* b2   = (const float*)d_in[11];
    float* out = (float*)d_out;

    char* p = (char*)d_ws;
    u16* norm   = (u16*)p;   p += (size_t)8192 * 256 * 2;
    u16* BtQKV  = (u16*)p;   p += (size_t)768 * 256 * 2;
    u16* W1t    = (u16*)p;   p += (size_t)256 * 256 * 2;
    u16* W2t    = (u16*)p;   p += (size_t)256 * 256 * 2;
    u16* Qb     = (u16*)p;   p += (size_t)NHT * SEQ * 64 * 2;
    u16* Kb     = (u16*)p;   p += (size_t)NHT * SEQ * 64 * 2;
    u16* Vb     = (u16*)p;   p += (size_t)NHT * SEQ * 64 * 2;
    float* D4   = (float*)p; p += (size_t)4 * NHT * SEQ * 4;
    u16* Vt     = (u16*)p;   p += (size_t)NHT * SEQ * 64 * 2;
    float* acat2= (float*)p; p += (size_t)2 * 8192 * 256 * 4;

    k_prep<<<1536, 256, 0, stream>>>(x, ln1w, ln1b, WQ, WK, WV, W1, W2,
                                     norm, BtQKV, W1t, W2t);
    k_qkv<<<dim3(128, 6), 256, 0, stream>>>(norm, BtQKV, Qb, Kb, Vb);
    k_pass1<<<dim3(32, 8, 4), 256, 0, stream>>>(Qb, Kb, D4);
    k_scaleV<<<dim3(64, 8), 256, 0, stream>>>(Vb, D4, Vt);
    k_pass2<<<dim3(64, 8, 2), 256, 0, stream>>>(Qb, Kb, Vt, acat2);
    k_tail<<<512, 256, 0, stream>>>(x, acat2, ln2w, ln2b, W1t, b1, W2t, b2, out);
}

// Round 10
// 243.293 us; speedup vs baseline: 1.8582x; 1.0590x over previous
//
#include <hip/hip_runtime.h>
#include <math.h>

#define SEQ 4096
#define CH  256
#define NHT 8      // N * HEADS
#define DHD 64

// Q is pre-scaled by log2(e)/64 at projection time, so both attention passes
// compute exp2(S) with zero multiplies.
#define QSCALE 0.0225421092f

using bf16x8 = __attribute__((ext_vector_type(8))) short;
using f32x4  = __attribute__((ext_vector_type(4))) float;
typedef unsigned short u16;
typedef unsigned int   u32;

__device__ __forceinline__ u16 f2bf(float f) {
    u32 u = __float_as_uint(f);
    u = (u + 0x7fffu + ((u >> 16) & 1u)) >> 16;
    return (u16)u;
}
__device__ __forceinline__ float bf2f(u16 h) {
    return __uint_as_float(((u32)h) << 16);
}
// raw v_exp_f32 — exp2f without -ffast-math is an OCML call (~8 VALU ops)
__device__ __forceinline__ float fexp2(float x) {
    return __builtin_amdgcn_exp2f(x);
}

// ---------------------------------------------------------------------------
// Prep: weight pack (blocks 0..1279) + LN1 (blocks 1280..1535), one launch.
// ---------------------------------------------------------------------------
__global__ __launch_bounds__(256) void k_prep(const float* __restrict__ x,
                                              const float* __restrict__ ln1w,
                                              const float* __restrict__ ln1b,
                                              const float* __restrict__ WQ,
                                              const float* __restrict__ WK,
                                              const float* __restrict__ WV,
                                              const float* __restrict__ W1,
                                              const float* __restrict__ W2,
                                              u16* __restrict__ norm,
                                              u16* __restrict__ BtQKV,
                                              u16* __restrict__ W1t,
                                              u16* __restrict__ W2t)
{
    __shared__ float tile[32][257];
    __shared__ float mu[32], rs[32];
    int bid = blockIdx.x;
    int t = threadIdx.x;
    if (bid < 1280) {   // ---- pack ----
        int id = bid * 256 + t;
        if (id < 768 * 256) {
            int j = id >> 8, c = id & 255;
            int which = j >> 8, h = (j >> 6) & 3, d = j & 63;
            const float* W = (which == 0) ? WQ : (which == 1) ? WK : WV;
            BtQKV[id] = f2bf(W[(h * 256 + c) * 64 + d]);
        } else if (id < 768 * 256 + 65536) {
            int jj = id - 768 * 256;
            int j = jj >> 8, c = jj & 255;
            W1t[jj] = f2bf(W1[c * 256 + j]);
        } else if (id < 768 * 256 + 2 * 65536) {
            int jj = id - 768 * 256 - 65536;
            int j = jj >> 8, c = jj & 255;
            W2t[jj] = f2bf(W2[c * 256 + j]);
        }
        return;
    }
    // ---- LN1 ----
    int b2i = bid - 1280;
    int n = b2i >> 7, s0 = (b2i & 127) * 32;
    int sl = t & 31, cg = t >> 5;
    for (int cc = 0; cc < 256; cc += 8) {
        int c = cc + cg;
        tile[sl][c] = x[(n * 256 + c) * SEQ + s0 + sl];
    }
    __syncthreads();
    int wv = t >> 6, l = t & 63;
    for (int rr = 0; rr < 8; rr++) {
        int s = wv * 8 + rr;
        float a0 = tile[s][l], a1 = tile[s][l + 64], a2 = tile[s][l + 128], a3 = tile[s][l + 192];
        float sm = a0 + a1 + a2 + a3;
        float sq = a0 * a0 + a1 * a1 + a2 * a2 + a3 * a3;
        for (int off = 32; off; off >>= 1) { sm += __shfl_xor(sm, off); sq += __shfl_xor(sq, off); }
        if (l == 0) {
            float m = sm * (1.f / 256.f);
            mu[s] = m;
            rs[s] = rsqrtf(sq * (1.f / 256.f) - m * m + 1e-5f);
        }
    }
    __syncthreads();
    float ww = ln1w[t], bb = ln1b[t];
    for (int s = 0; s < 32; s++) {
        float v = (tile[s][t] - mu[s]) * rs[s] * ww + bb;
        norm[(n * SEQ + s0 + s) * 256 + t] = f2bf(v);
    }
}

// ---------------------------------------------------------------------------
// QKV projection, barrier-free (R4-proven). Q pre-scaled by QSCALE.
// R10: V is written DIRECTLY TRANSPOSED (Vt[nh][d][k], raw — no 1/D scale;
// pass2 folds 1/D via exp2(S - log2 D)). The 4 r-values are s-consecutive ->
// one packed uint2 store.
// ---------------------------------------------------------------------------
__global__ __launch_bounds__(256) void k_qkv(const u16* __restrict__ norm,
                                             const u16* __restrict__ Bt,
                                             u16* __restrict__ Qo,
                                             u16* __restrict__ Ko,
                                             u16* __restrict__ Vto)
{
    int m0 = blockIdx.x * 64, j0 = blockIdx.y * 128;
    int t = threadIdx.x, w = t >> 6, lane = t & 63, quad = lane >> 4, l16 = lane & 15;
    const u16* Ap = norm + (long)(m0 + w * 16 + l16) * 256;
    const u16* Bp = Bt + (long)j0 * 256;
    f32x4 z = {0.f, 0.f, 0.f, 0.f};
    f32x4 acc[8];
    #pragma unroll
    for (int j = 0; j < 8; j++) acc[j] = z;
    #pragma unroll
    for (int kc = 0; kc < 8; kc++) {
        bf16x8 a = *(const bf16x8*)&Ap[kc * 32 + quad * 8];
        #pragma unroll
        for (int j = 0; j < 8; j++) {
            bf16x8 b = *(const bf16x8*)&Bp[(long)(j * 16 + l16) * 256 + kc * 32 + quad * 8];
            acc[j] = __builtin_amdgcn_mfma_f32_16x16x32_bf16(a, b, acc[j], 0, 0, 0);
        }
    }
    #pragma unroll
    for (int j = 0; j < 8; j++) {
        int col = j0 + j * 16 + l16;
        int which = col >> 8, h = (col >> 6) & 3, d = col & 63;
        int m = m0 + w * 16 + quad * 4;
        int n = m >> 12, s = m & 4095;
        if (which == 2) {
            u16 h0 = f2bf(acc[j][0]), h1 = f2bf(acc[j][1]);
            u16 h2_ = f2bf(acc[j][2]), h3 = f2bf(acc[j][3]);
            uint2 pk;
            pk.x = (u32)h0 | ((u32)h1 << 16);
            pk.y = (u32)h2_ | ((u32)h3 << 16);
            *(uint2*)&Vto[((long)(n * 4 + h) * 64 + d) * SEQ + s] = pk;
        } else {
            u16* dst = (which == 0) ? Qo : Ko;
            float sc = (which == 0) ? QSCALE : 1.0f;
            #pragma unroll
            for (int r = 0; r < 4; r++)
                dst[((n * 4 + h) * SEQ + s + r) * 64 + d] = f2bf(acc[j][r] * sc);
        }
    }
}

// ---------------------------------------------------------------------------
// Pass 1, wave-split-q (R8-proven), raw v_exp_f32. Grid (32, 8, 4).
// ---------------------------------------------------------------------------
__global__ __launch_bounds__(256) void k_pass1(const u16* __restrict__ Q,
                                               const u16* __restrict__ Km,
                                               float* __restrict__ D4)
{
    __shared__ float Dred[128];
    int nh = blockIdx.y, k0 = blockIdx.x * 128, qc = blockIdx.z;
    const u16* Qh = Q + (long)nh * SEQ * 64;
    const u16* Kh = Km + (long)nh * SEQ * 64;
    int t = threadIdx.x, w = t >> 6, lane = t & 63, quad = lane >> 4, l16 = lane & 15;
    bf16x8 Kf[8][2];
    #pragma unroll
    for (int i = 0; i < 8; i++) {
        Kf[i][0] = *(const bf16x8*)&Kh[(k0 + i * 16 + l16) * 64 + quad * 8];
        Kf[i][1] = *(const bf16x8*)&Kh[(k0 + i * 16 + l16) * 64 + 32 + quad * 8];
    }
    if (t < 128) Dred[t] = 0.f;
    f32x4 z = {0.f, 0.f, 0.f, 0.f};
    float Dacc[8][4] = {};
    const int qw0 = qc * 1024 + w * 256;
    bf16x8 b0 = *(const bf16x8*)&Qh[(qw0 + l16) * 64 + quad * 8];
    bf16x8 b1 = *(const bf16x8*)&Qh[(qw0 + l16) * 64 + 32 + quad * 8];
    for (int step = 0; step < 16; step++) {
        int q = qw0 + step * 16;
        bf16x8 n0, n1;
        if (step < 15) {
            n0 = *(const bf16x8*)&Qh[(q + 16 + l16) * 64 + quad * 8];
            n1 = *(const bf16x8*)&Qh[(q + 16 + l16) * 64 + 32 + quad * 8];
        }
        #pragma unroll
        for (int i = 0; i < 8; i++) {
            f32x4 acc = z;
            acc = __builtin_amdgcn_mfma_f32_16x16x32_bf16(Kf[i][0], b0, acc, 0, 0, 0);
            acc = __builtin_amdgcn_mfma_f32_16x16x32_bf16(Kf[i][1], b1, acc, 0, 0, 0);
            #pragma unroll
            for (int r = 0; r < 4; r++) Dacc[i][r] += fexp2(acc[r]);
        }
        b0 = n0; b1 = n1;
    }
    #pragma unroll
    for (int i = 0; i < 8; i++)
        #pragma unroll
        for (int r = 0; r < 4; r++) {
            float v = Dacc[i][r];
            v += __shfl_xor(v, 1); v += __shfl_xor(v, 2);
            v += __shfl_xor(v, 4); v += __shfl_xor(v, 8);
            Dacc[i][r] = v;
        }
    __syncthreads();
    if (l16 == 0) {
        #pragma unroll
        for (int i = 0; i < 8; i++)
            #pragma unroll
            for (int r = 0; r < 4; r++)
                atomicAdd(&Dred[i * 16 + quad * 4 + r], Dacc[i][r]);
    }
    __syncthreads();
    if (t < 128) D4[((long)(qc * NHT + nh)) * SEQ + k0 + t] = Dred[t];
}

// ---------------------------------------------------------------------------
// Pass 2, SOFTWARE-PIPELINED wave-split-k.  R10 deltas:
//  - 1/D folded as exp2(S - Lk[k]); Lk = log2(sum of D4 partials), computed
//    once per block into LDS (kills the k_scaleV kernel; V^T arrives raw).
//  - Pipelined body: write P(i) | read L(i+1) | ST(i+1) (K frags loaded last
//    body) | reload kA=K(i+2) | read P(i) | PV(i) (vb loaded last body) |
//    load vb=V(i+1).  Every global load has >=half-body distance; the LDS
//    write->read turnaround is covered by 16 MFMAs + 32 exps.  In-order DS
//    per wave makes the single lP buffer safe with no barriers.
// Grid (64 q-tiles, 8 nh, 2 k-chunks).
// ---------------------------------------------------------------------------
__global__ __launch_bounds__(256) void k_pass2(const u16* __restrict__ Q,
                                               const u16* __restrict__ Km,
                                               const u16* __restrict__ Vt,
                                               const float* __restrict__ D4,
                                               float* __restrict__ acat2)
{
    __shared__ __align__(16) unsigned char smem[34816];
    u16 (*lP)[64][36] = (u16(*)[64][36])smem;               // 18432 B
    float* Lk = (float*)(smem + 18432);                     // 8192 B (dead by epilogue)
    float (*SA)[68] = (float(*)[68])smem;                   // epilogue overlay
    float (*SB)[68] = (float(*)[68])(smem + 17408);

    int nh = blockIdx.y, q0 = blockIdx.x * 64, kcid = blockIdx.z;
    int n = nh >> 2, h = nh & 3;
    const u16* Qh = Q + (long)nh * SEQ * 64;
    const u16* Kh = Km + (long)nh * SEQ * 64;
    const u16* Vh = Vt + (long)nh * 64 * SEQ;
    int t = threadIdx.x, w = t >> 6, lane = t & 63, quad = lane >> 4, l16 = lane & 15;
    const int kw0 = kcid * 2048 + w * 512;
    const int klw = w * 512;

    // ---- Lk[kl] = log2(sum of 4 D4 partials), block's 2048-k window ----
    {
        const float* Dp = D4 + (long)nh * SEQ + kcid * 2048;
        const long QS = (long)NHT * SEQ;
        #pragma unroll
        for (int off = 0; off < 8; off++) {
            int kl = off * 256 + t;
            float s = Dp[kl] + Dp[QS + kl] + Dp[2 * QS + kl] + Dp[3 * QS + kl];
            Lk[kl] = __log2f(s);
        }
    }
    // Q frags + K(0) frags (issued before barrier to cover latency)
    bf16x8 Qf[4][2];
    #pragma unroll
    for (int jq = 0; jq < 4; jq++)
        #pragma unroll
        for (int ch = 0; ch < 2; ch++)
            Qf[jq][ch] = *(const bf16x8*)&Qh[(q0 + jq * 16 + l16) * 64 + ch * 32 + quad * 8];
    bf16x8 kA[2][2];
    #pragma unroll
    for (int ksub = 0; ksub < 2; ksub++) {
        kA[ksub][0] = *(const bf16x8*)&Kh[(kw0 + ksub * 16 + l16) * 64 + quad * 8];
        kA[ksub][1] = *(const bf16x8*)&Kh[(kw0 + ksub * 16 + l16) * 64 + 32 + quad * 8];
    }
    f32x4 z = {0.f, 0.f, 0.f, 0.f};
    f32x4 accO[4][4];
    #pragma unroll
    for (int jq = 0; jq < 4; jq++)
        #pragma unroll
        for (int jd = 0; jd < 4; jd++) accO[jq][jd] = z;
    __syncthreads();

    // ---- ST(0) ----
    uint2 pk[2][4];
    {
        f32x4 Lv[2];
        #pragma unroll
        for (int ksub = 0; ksub < 2; ksub++)
            Lv[ksub] = *(const f32x4*)&Lk[klw + ksub * 16 + quad * 4];
        #pragma unroll
        for (int ksub = 0; ksub < 2; ksub++)
            #pragma unroll
            for (int jq = 0; jq < 4; jq++) {
                f32x4 acc = z;
                acc = __builtin_amdgcn_mfma_f32_16x16x32_bf16(kA[ksub][0], Qf[jq][0], acc, 0, 0, 0);
                acc = __builtin_amdgcn_mfma_f32_16x16x32_bf16(kA[ksub][1], Qf[jq][1], acc, 0, 0, 0);
                u32 e0 = __float_as_uint(fexp2(acc[0] - Lv[ksub][0]));
                u32 e1 = __float_as_uint(fexp2(acc[1] - Lv[ksub][1]));
                u32 e2 = __float_as_uint(fexp2(acc[2] - Lv[ksub][2]));
                u32 e3 = __float_as_uint(fexp2(acc[3] - Lv[ksub][3]));
                pk[ksub][jq].x = __builtin_amdgcn_perm(e1, e0, 0x07060302u);
                pk[ksub][jq].y = __builtin_amdgcn_perm(e3, e2, 0x07060302u);
            }
    }
    // kA <- K(1); vb <- V(0)
    #pragma unroll
    for (int ksub = 0; ksub < 2; ksub++) {
        kA[ksub][0] = *(const bf16x8*)&Kh[(kw0 + 32 + ksub * 16 + l16) * 64 + quad * 8];
        kA[ksub][1] = *(const bf16x8*)&Kh[(kw0 + 32 + ksub * 16 + l16) * 64 + 32 + quad * 8];
    }
    bf16x8 vb[4];
    #pragma unroll
    for (int jd = 0; jd < 4; jd++)
        vb[jd] = *(const bf16x8*)&Vh[(jd * 16 + l16) * SEQ + kw0 + quad * 8];

    for (int i = 0; i < 16; i++) {
        int k0 = kw0 + i * 32;
        // write P(i)
        #pragma unroll
        for (int ksub = 0; ksub < 2; ksub++)
            #pragma unroll
            for (int jq = 0; jq < 4; jq++)
                *(uint2*)&lP[w][jq * 16 + l16][ksub * 16 + quad * 4] = pk[ksub][jq];
        if (i < 15) {
            f32x4 Lv[2];
            #pragma unroll
            for (int ksub = 0; ksub < 2; ksub++)
                Lv[ksub] = *(const f32x4*)&Lk[klw + (i + 1) * 32 + ksub * 16 + quad * 4];
            // ST(i+1) with kA = K(i+1) (loaded one body ago)
            #pragma unroll
            for (int ksub = 0; ksub < 2; ksub++)
                #pragma unroll
                for (int jq = 0; jq < 4; jq++) {
                    f32x4 acc = z;
                    acc = __builtin_amdgcn_mfma_f32_16x16x32_bf16(kA[ksub][0], Qf[jq][0], acc, 0, 0, 0);
                    acc = __builtin_amdgcn_mfma_f32_16x16x32_bf16(kA[ksub][1], Qf[jq][1], acc, 0, 0, 0);
                    u32 e0 = __float_as_uint(fexp2(acc[0] - Lv[ksub][0]));
                    u32 e1 = __float_as_uint(fexp2(acc[1] - Lv[ksub][1]));
                    u32 e2 = __float_as_uint(fexp2(acc[2] - Lv[ksub][2]));
                    u32 e3 = __float_as_uint(fexp2(acc[3] - Lv[ksub][3]));
                    pk[ksub][jq].x = __builtin_amdgcn_perm(e1, e0, 0x07060302u);
                    pk[ksub][jq].y = __builtin_amdgcn_perm(e3, e2, 0x07060302u);
                }
            if (i < 14) {   // kA <- K(i+2), straight into the (now dead) regs
                #pragma unroll
                for (int ksub = 0; ksub < 2; ksub++) {
                    kA[ksub][0] = *(const bf16x8*)&Kh[(k0 + 64 + ksub * 16 + l16) * 64 + quad * 8];
                    kA[ksub][1] = *(const bf16x8*)&Kh[(k0 + 64 + ksub * 16 + l16) * 64 + 32 + quad * 8];
                }
            }
        }
        // PV(i): read own lP strip (ordered after this body's writes per-wave)
        #pragma unroll
        for (int jq = 0; jq < 4; jq++) {
            bf16x8 pa = *(const bf16x8*)&lP[w][jq * 16 + l16][quad * 8];
            #pragma unroll
            for (int jd = 0; jd < 4; jd++)
                accO[jq][jd] = __builtin_amdgcn_mfma_f32_16x16x32_bf16(pa, vb[jd], accO[jq][jd], 0, 0, 0);
        }
        if (i < 15) {   // vb <- V(i+1), full-body distance to next use
            #pragma unroll
            for (int jd = 0; jd < 4; jd++)
                vb[jd] = *(const bf16x8*)&Vh[(jd * 16 + l16) * SEQ + k0 + 32 + quad * 8];
        }
    }
    // ---- cross-wave reduction + coalesced partial store (R7-proven) ----
    __syncthreads();
    if (w >= 2) {
        float (*S)[68] = (w == 2) ? SA : SB;
        #pragma unroll
        for (int jq = 0; jq < 4; jq++)
            #pragma unroll
            for (int jd = 0; jd < 4; jd++)
                #pragma unroll
                for (int r = 0; r < 4; r++)
                    S[jq * 16 + quad * 4 + r][jd * 16 + l16] = accO[jq][jd][r];
    }
    __syncthreads();
    if (w < 2) {
        float (*S)[68] = (w == 0) ? SA : SB;
        #pragma unroll
        for (int jq = 0; jq < 4; jq++)
            #pragma unroll
            for (int jd = 0; jd < 4; jd++)
                #pragma unroll
                for (int r = 0; r < 4; r++) {
                    float v = accO[jq][jd][r] + S[jq * 16 + quad * 4 + r][jd * 16 + l16];
                    S[jq * 16 + quad * 4 + r][jd * 16 + l16] = v;
                }
    }
    __syncthreads();
    float* dst = acat2 + (long)kcid * 8192 * 256;
    #pragma unroll
    for (int p = 0; p < 4; p++) {
        int row = p * 16 + (t >> 4);
        int ch = (t & 15) * 4;
        float4 va = *(float4*)&SA[row][ch];
        float4 vb2 = *(float4*)&SB[row][ch];
        float4 o = make_float4(va.x + vb2.x, va.y + vb2.y, va.z + vb2.z, va.w + vb2.w);
        *(float4*)&dst[((long)n * SEQ + q0 + row) * 256 + h * 64 + ch] = o;
    }
}

// ---------------------------------------------------------------------------
// Fused tail: LN2 + MLP + residual + transposed store (R9-proven).
// ---------------------------------------------------------------------------
__global__ __launch_bounds__(256) void k_tail(const float* __restrict__ x,
                                              const float* __restrict__ acat2,
                                              const float* __restrict__ lnw,
                                              const float* __restrict__ lnb,
                                              const u16* __restrict__ W1t,
                                              const float* __restrict__ b1v,
                                              const u16* __restrict__ W2t,
                                              const float* __restrict__ b2v,
                                              float* __restrict__ out)
{
    __shared__ __align__(16) unsigned char smem[16448];  // tile fp32 / lT u16
    float (*tile)[257] = (float(*)[257])smem;            // [16][257]
    u16 (*lT)[264] = (u16(*)[264])smem;                  // [16][264] overlay
    __shared__ float mu[16], rs[16];
    __shared__ __align__(16) u16 lH[16][264];

    const long STRIDE = (long)8192 * 256;
    int m0 = blockIdx.x * 16;
    int n = m0 >> 12, s0 = m0 & 4095;
    int t = threadIdx.x, w = t >> 6, lane = t & 63, quad = lane >> 4, l16 = lane & 15;

    {
        int sl = t & 15, cg = t >> 4;
        for (int cc = 0; cc < 256; cc += 16) {
            int c = cc + cg;
            tile[sl][c] = x[(n * 256 + c) * SEQ + s0 + sl];
        }
    }
    __syncthreads();
    for (int s = 0; s < 16; s++) {
        long idx = (long)(m0 + s) * 256 + t;
        tile[s][t] += acat2[idx] + acat2[idx + STRIDE];
    }
    __syncthreads();
    {
        int l = t & 63;
        for (int rr = 0; rr < 4; rr++) {
            int s = w * 4 + rr;
            float a0 = tile[s][l], a1 = tile[s][l + 64], a2 = tile[s][l + 128], a3 = tile[s][l + 192];
            float sm = a0 + a1 + a2 + a3;
            float sq = a0 * a0 + a1 * a1 + a2 * a2 + a3 * a3;
            for (int off = 32; off; off >>= 1) { sm += __shfl_xor(sm, off); sq += __shfl_xor(sq, off); }
            if (l == 0) {
                float m = sm * (1.f / 256.f);
                mu[s] = m;
                rs[s] = rsqrtf(sq * (1.f / 256.f) - m * m + 1e-5f);
            }
        }
    }
    __syncthreads();
    {
        float ww = lnw[t], bb = lnb[t];
        for (int s = 0; s < 16; s++)
            lH[s][t] = f2bf((tile[s][t] - mu[s]) * rs[s] * ww + bb);
    }
    __syncthreads();

    f32x4 z = {0.f, 0.f, 0.f, 0.f};
    f32x4 acc1[4];
    #pragma unroll
    for (int js = 0; js < 4; js++) acc1[js] = z;
    #pragma unroll
    for (int kc = 0; kc < 8; kc++) {
        bf16x8 b = *(const bf16x8*)&lH[l16][kc * 32 + quad * 8];
        #pragma unroll
        for (int js = 0; js < 4; js++) {
            bf16x8 a = *(const bf16x8*)&W1t[(long)(w * 64 + js * 16 + l16) * 256 + kc * 32 + quad * 8];
            acc1[js] = __builtin_amdgcn_mfma_f32_16x16x32_bf16(a, b, acc1[js], 0, 0, 0);
        }
    }
    #pragma unroll
    for (int js = 0; js < 4; js++) {
        u32 e[4];
        #pragma unroll
        for (int r = 0; r < 4; r++) {
            int j = w * 64 + js * 16 + quad * 4 + r;
            float v = acc1[js][r] + b1v[j];
            float g = 0.5f * v * (1.f + erff(v * 0.70710678118f));
            u32 u = __float_as_uint(g);
            e[r] = u + 0x7fffu + ((u >> 16) & 1u);
        }
        uint2 pk;
        pk.x = __builtin_amdgcn_perm(e[1], e[0], 0x07060302u);
        pk.y = __builtin_amdgcn_perm(e[3], e[2], 0x07060302u);
        *(uint2*)&lT[l16][w * 64 + js * 16 + quad * 4] = pk;
    }
    __syncthreads();
    f32x4 acc2[4];
    #pragma unroll
    for (int cs = 0; cs < 4; cs++) acc2[cs] = z;
    #pragma unroll
    for (int kc = 0; kc < 8; kc++) {
        bf16x8 pa = *(const bf16x8*)&lT[l16][kc * 32 + quad * 8];
        #pragma unroll
        for (int cs = 0; cs < 4; cs++) {
            bf16x8 wb = *(const bf16x8*)&W2t[(long)(w * 64 + cs * 16 + l16) * 256 + kc * 32 + quad * 8];
            acc2[cs] = __builtin_amdgcn_mfma_f32_16x16x32_bf16(pa, wb, acc2[cs], 0, 0, 0);
        }
    }
    #pragma unroll
    for (int cs = 0; cs < 4; cs++) {
        int c = w * 64 + cs * 16 + l16;
        float bj = b2v[c];
        float vv[4];
        #pragma unroll
        for (int r = 0; r < 4; r++) {
            long idx = (long)(m0 + quad * 4 + r) * 256 + c;
            vv[r] = acc2[cs][r] + bj + acat2[idx] + acat2[idx + STRIDE];
        }
        float4 o = make_float4(vv[0], vv[1], vv[2], vv[3]);
        *(float4*)&out[((long)n * 256 + c) * SEQ + s0 + quad * 4] = o;
    }
}

// ---------------------------------------------------------------------------
extern "C" void kernel_launch(void* const* d_in, const int* in_sizes, int n_in,
                              void* d_out, int out_size, void* d_ws, size_t ws_size,
                              hipStream_t stream) {
    const float* x    = (const float*)d_in[0];
    const float* ln1w = (const float*)d_in[1];
    const float* ln1b = (const float*)d_in[2];
    const float* WQ   = (const float*)d_in[3];
    const float* WK   = (const float*)d_in[4];
    const float* WV   = (const float*)d_in[5];
    const float* ln2w = (const float*)d_in[6];
    const float* ln2b = (const float*)d_in[7];
    const float* W1   = (const float*)d_in[8];
    const float* b1   = (const float*)d_in[9];
    const float* W2   = (const float*)d_in[10];
    const float* b2   = (const float*)d_in[11];
    float* out = (float*)d_out;

    char* p = (char*)d_ws;
    u16* norm   = (u16*)p;   p += (size_t)8192 * 256 * 2;
    u16* BtQKV  = (u16*)p;   p += (size_t)768 * 256 * 2;
    u16* W1t    = (u16*)p;   p += (size_t)256 * 256 * 2;
    u16* W2t    = (u16*)p;   p += (size_t)256 * 256 * 2;
    u16* Qb     = (u16*)p;   p += (size_t)NHT * SEQ * 64 * 2;
    u16* Kb     = (u16*)p;   p += (size_t)NHT * SEQ * 64 * 2;
    u16* VtT    = (u16*)p;   p += (size_t)NHT * SEQ * 64 * 2;
    float* D4   = (float*)p; p += (size_t)4 * NHT * SEQ * 4;
    float* acat2= (float*)p; p += (size_t)2 * 8192 * 256 * 4;

    k_prep<<<1536, 256, 0, stream>>>(x, ln1w, ln1b, WQ, WK, WV, W1, W2,
                                     norm, BtQKV, W1t, W2t);
    k_qkv<<<dim3(128, 6), 256, 0, stream>>>(norm, BtQKV, Qb, Kb, VtT);
    k_pass1<<<dim3(32, 8, 4), 256, 0, stream>>>(Qb, Kb, D4);
    k_pass2<<<dim3(64, 8, 2), 256, 0, stream>>>(Qb, Kb, VtT, D4, acat2);
    k_tail<<<512, 256, 0, stream>>>(x, acat2, ln2w, ln2b, W1t, b1, W2t, b2, out);
}